// Round 18
// baseline (3284.274 us; speedup 1.0000x reference)
//
#include <hip/hip_runtime.h>
#include <math.h>
#include <stdint.h>

typedef _Float16 f16x8 __attribute__((ext_vector_type(8)));
typedef __attribute__((ext_vector_type(4))) float f32x4;

#define MFMA16(a, b, c) __builtin_amdgcn_mfma_f32_16x16x32_f16(a, b, c, 0, 0, 0)

union H16 { _Float16 f; ushort u; };
union HF8 { ushort u[8]; f16x8 v; };

__device__ __forceinline__ ushort f2h(float x) { H16 t; t.f = (_Float16)x; return t.u; }
__device__ __forceinline__ float h2f(ushort u) { H16 t; t.u = u; return (float)t.f; }
__device__ __forceinline__ void split_h(float x, ushort& h, ushort& l) {
  h = f2h(x);
  l = f2h(x - h2f(h));
}
__device__ __forceinline__ f16x8 ldh8(const ushort* p) { return *(const f16x8*)p; }

__device__ __forceinline__ float silu_f(float x) {
  float e = __builtin_amdgcn_exp2f(x * -1.44269504089f);
  return x * __builtin_amdgcn_rcpf(1.f + e);
}
__device__ __forceinline__ float gelu_f(float x) {
  float z = fabsf(x) * 0.70710678118654752f;
  float t = __builtin_amdgcn_rcpf(fmaf(0.3275911f, z, 1.f));
  float poly = t * (0.254829592f + t * (-0.284496736f + t * (1.421413741f +
               t * (-1.453152027f + t * 1.061405429f))));
  float e = __builtin_amdgcn_exp2f(-z * z * 1.44269504089f);
  float erfz = copysignf(1.f - poly * e, x);
  return 0.5f * x * (1.f + erfz);
}

// write-drain barrier: LDS writes visible, global loads stay in flight
__device__ __forceinline__ void lgkm_barrier() {
  asm volatile("s_waitcnt lgkmcnt(0)" ::: "memory");
  __builtin_amdgcn_s_barrier();
}

// Fragment-linear: buffer[rt][kt][lane][8] ushorts (tile=512).
// A-frag: lane holds row lane&15, k=kt*32+(lane>>4)*8+e.
// C-frag [m89]: col=lane&15(+g*16), row=(lane>>4)*4+r(+f*16).
// LDS hand-off: single fp16 plane, 512 ushorts/tile, XOR swizzle:
//   idx = ((q*16+t)*8+e) ^ (((t>>2)&3)*8); read b128 at (lane*8)^swz.

__device__ __forceinline__ f16x8 rdtile16(const ushort* src, int T, int lane) {
  int idx = T * 512 + ((lane * 8) ^ (((lane >> 2) & 3) * 8));
  return *(const f16x8*)&src[idx];
}

// ---------------------------------------------------------------------------
// KA: F_br = LN_br(silu(X @ W1b + b1) @ W2b + b2).  64 tok/block, branch =
// blockIdx.y. 4 phases x 2 slabs; A persistent in regs (kt FULLY unrolled —
// rule #20: partial unroll => runtime index => scratch spill, r17 lesson).
// ---------------------------------------------------------------------------
__global__ __launch_bounds__(512) void k_lin12(
    const ushort* __restrict__ Xh,
    const ushort* __restrict__ fW1h, const ushort* __restrict__ fW1l,
    const ushort* __restrict__ bW1h, const ushort* __restrict__ bW1l,
    const ushort* __restrict__ fW2h, const ushort* __restrict__ fW2l,
    const ushort* __restrict__ bW2h, const ushort* __restrict__ bW2l,
    const float* __restrict__ fb1, const float* __restrict__ bb1,
    const float* __restrict__ fb2, const float* __restrict__ bb2,
    const float* __restrict__ flw, const float* __restrict__ flb,
    const float* __restrict__ blw, const float* __restrict__ blb,
    ushort* __restrict__ Fh) {
  __shared__ __align__(16) char lraw[36864];
  __shared__ float st[512];
  ushort* Hs16 = (ushort*)lraw;  // [2 dbuf][2 slab][4096] ushorts = 32KB
  float* trw = (float*)lraw;     // [8][1088] (epilogue alias)

  const int tid = threadIdx.x, lane = tid & 63, w = tid >> 6;
  const int h = w >> 2, c = w & 3;
  const int blk = blockIdx.x, br = blockIdx.y;
  const ushort* W1h = br ? bW1h : fW1h; const ushort* W1l = br ? bW1l : fW1l;
  const ushort* W2h = br ? bW2h : fW2h; const ushort* W2l = br ? bW2l : fW2l;
  const float* b1 = br ? bb1 : fb1;
  const float* b2 = br ? bb2 : fb2;
  const float* lw = br ? blw : flw;
  const float* lb = br ? blb : flb;

  // persistent A fragments: 16 x f16x8 = 64 VGPR (all accesses compile-time)
  f16x8 Areg[2][8];
#pragma unroll
  for (int f = 0; f < 2; ++f)
#pragma unroll
    for (int kt = 0; kt < 8; ++kt)
      Areg[f][kt] = ldh8(&Xh[((size_t)(blk * 4 + h * 2 + f) * 8 + kt) * 512 + lane * 8]);

  f32x4 acc[2][4];
#pragma unroll
  for (int f = 0; f < 2; ++f)
#pragma unroll
    for (int g = 0; g < 4; ++g) acc[f][g] = (f32x4){0.f, 0.f, 0.f, 0.f};

  // gemm1 for a phase: both slabs (2p, 2p+1); A from registers; kt FULL unroll.
  auto gemm1p = [&](int p, f32x4 a1[2][2]) {
#pragma unroll
    for (int kt = 0; kt < 8; ++kt) {
#pragma unroll
      for (int sl = 0; sl < 2; ++sl) {
        int s = p * 2 + sl;
        size_t wt = ((size_t)(s * 4 + c) * 8 + kt) * 512 + lane * 8;
        f16x8 bh = ldh8(&W1h[wt]), bl = ldh8(&W1l[wt]);
#pragma unroll
        for (int f = 0; f < 2; ++f) {
          a1[sl][f] = MFMA16(Areg[f][kt], bh, a1[sl][f]);
          a1[sl][f] = MFMA16(Areg[f][kt], bl, a1[sl][f]);
        }
      }
    }
  };
  auto hswrp = [&](int p, f32x4 a1[2][2]) {
    const int ktile = c >> 1;
    const int q = (c & 1) * 2 + ((lane & 15) >> 3);
    const int e = lane & 7;
#pragma unroll
    for (int sl = 0; sl < 2; ++sl) {
      int s = p * 2 + sl;
      ushort* dst = Hs16 + (p & 1) * 8192 + sl * 4096;
      const float bias1 = b1[s * 64 + c * 16 + (lane & 15)];
#pragma unroll
      for (int f = 0; f < 2; ++f) {
        const int rt = h * 2 + f;
#pragma unroll
        for (int r = 0; r < 4; ++r) {
          float x = silu_f(a1[sl][f][r] + bias1);
          int t16 = (lane >> 4) * 4 + r;
          int idx = ((q * 16 + t16) * 8 + e) ^ (((t16 >> 2) & 3) * 8);
          dst[(rt * 2 + ktile) * 512 + idx] = f2h(x);
        }
      }
    }
  };

  {
    f32x4 a1[2][2] = {};
    gemm1p(0, a1); hswrp(0, a1);
  }
#pragma unroll 1
  for (int p = 0; p < 4; ++p) {
    lgkm_barrier();
    const ushort* src = Hs16 + (p & 1) * 8192;
#pragma unroll
    for (int sl = 0; sl < 2; ++sl) {
      int s = p * 2 + sl;
#pragma unroll
      for (int ks = 0; ks < 2; ++ks) {
        f16x8 hh2[2];
#pragma unroll
        for (int f = 0; f < 2; ++f)
          hh2[f] = rdtile16(src, sl * 8 + (h * 2 + f) * 2 + ks, lane);
#pragma unroll
        for (int g = 0; g < 4; ++g) {
          size_t wt = ((size_t)(c * 4 + g) * 16 + (s * 2 + ks)) * 512 + lane * 8;
          f16x8 bh = ldh8(&W2h[wt]), bl = ldh8(&W2l[wt]);
#pragma unroll
          for (int f = 0; f < 2; ++f) {
            acc[f][g] = MFMA16(hh2[f], bh, acc[f][g]);
            acc[f][g] = MFMA16(hh2[f], bl, acc[f][g]);
          }
        }
      }
    }
    if (p < 3) {
      f32x4 a1[2][2] = {};
      gemm1p(p + 1, a1); hswrp(p + 1, a1);
    }
  }
  __syncthreads();  // all Hs reads done; trw aliases the region

  // epilogue: bias2 + branch LN; coalesced via per-wave padded transpose
  float* mytr = trw + w * 1088;
  const int lr = lane >> 2, cb = (lane & 3) * 16;
  const int colL = c * 64 + cb;
  float y[2][16];
#pragma unroll
  for (int f = 0; f < 2; ++f) {
#pragma unroll
    for (int g = 0; g < 4; ++g)
#pragma unroll
      for (int r = 0; r < 4; ++r)
        mytr[((lane >> 4) * 4 + r) * 68 + g * 16 + (lane & 15)] = acc[f][g][r];
    float s1 = 0.f, s2 = 0.f;
#pragma unroll
    for (int i = 0; i < 4; ++i) {
      float4 t = *(const float4*)&mytr[lr * 68 + cb + i * 4];
      float4 bb = *(const float4*)&b2[colL + i * 4];
      y[f][i * 4 + 0] = t.x + bb.x; y[f][i * 4 + 1] = t.y + bb.y;
      y[f][i * 4 + 2] = t.z + bb.z; y[f][i * 4 + 3] = t.w + bb.w;
#pragma unroll
      for (int q2 = 0; q2 < 4; ++q2) { float v = y[f][i * 4 + q2]; s1 += v; s2 += v * v; }
    }
    s1 += __shfl_xor(s1, 1, 64); s2 += __shfl_xor(s2, 1, 64);
    s1 += __shfl_xor(s1, 2, 64); s2 += __shfl_xor(s2, 2, 64);
    if ((lane & 3) == 0) {
      int tl = h * 32 + f * 16 + lr;
      st[tl * 8 + c * 2] = s1; st[tl * 8 + c * 2 + 1] = s2;
    }
  }
  lgkm_barrier();
#pragma unroll
  for (int f = 0; f < 2; ++f) {
    int tl = h * 32 + f * 16 + lr;
    float s1 = st[tl * 8] + st[tl * 8 + 2] + st[tl * 8 + 4] + st[tl * 8 + 6];
    float s2 = st[tl * 8 + 1] + st[tl * 8 + 3] + st[tl * 8 + 5] + st[tl * 8 + 7];
    float mu = s1 * (1.f / 256.f);
    float rs = rsqrtf(s2 * (1.f / 256.f) - mu * mu + 1e-5f);
    HF8 h0, h1;
#pragma unroll
    for (int i = 0; i < 16; ++i) {
      float z = (y[f][i] - mu) * rs * lw[colL + i] + lb[colL + i];
      if (i < 8) h0.u[i] = f2h(z); else h1.u[i - 8] = f2h(z);
    }
    int R = blk * 64 + tl;
    int Cg = br * 256 + colL;
    size_t base = ((size_t)(R >> 4) * 16 + (Cg >> 5)) * 512;
    int q0 = (Cg & 31) >> 3;
    *(f16x8*)&Fh[base + (q0 * 16 + lr) * 8] = h0.v;
    *(f16x8*)&Fh[base + ((q0 + 1) * 16 + lr) * 8] = h1.v;
  }
}

// ---------------------------------------------------------------------------
// KB: M = F @ mg + b; Xc = LN(resid + M, nm); Hb = LN(Xc, ffn).
// ---------------------------------------------------------------------------
__global__ __launch_bounds__(512) void k_mergep(
    const ushort* __restrict__ Fh,
    const ushort* __restrict__ Mh, const ushort* __restrict__ Ml,
    const float* __restrict__ mgb,
    const ushort* __restrict__ Rh, const ushort* __restrict__ Rl,
    const float* __restrict__ nmw, const float* __restrict__ nmb,
    const float* __restrict__ fw, const float* __restrict__ fb,
    ushort* __restrict__ Xch, ushort* __restrict__ Xcl,
    ushort* __restrict__ Hbh) {
  __shared__ float trw[8][1088];
  __shared__ float st[512], stB[512];
  const int tid = threadIdx.x, lane = tid & 63, w = tid >> 6;
  const int h = w >> 2, c = w & 3;
  const int blk = blockIdx.x;

  f32x4 acc[2][4];
#pragma unroll
  for (int f = 0; f < 2; ++f)
#pragma unroll
    for (int g = 0; g < 4; ++g) acc[f][g] = (f32x4){0.f, 0.f, 0.f, 0.f};

#pragma unroll 2
  for (int kt = 0; kt < 16; ++kt) {
    f16x8 ah[2];
#pragma unroll
    for (int f = 0; f < 2; ++f) {
      size_t at = ((size_t)(blk * 4 + h * 2 + f) * 16 + kt) * 512 + lane * 8;
      ah[f] = ldh8(&Fh[at]);
    }
#pragma unroll
    for (int g = 0; g < 4; ++g) {
      size_t wt = ((size_t)(c * 4 + g) * 16 + kt) * 512 + lane * 8;
      f16x8 bh = ldh8(&Mh[wt]), bl = ldh8(&Ml[wt]);
#pragma unroll
      for (int f = 0; f < 2; ++f) {
        acc[f][g] = MFMA16(ah[f], bh, acc[f][g]);
        acc[f][g] = MFMA16(ah[f], bl, acc[f][g]);
      }
    }
  }

  float* mytr = &trw[w][0];
  const int lr = lane >> 2, cb = (lane & 3) * 16;
  const int colL = c * 64 + cb;
  float y[2][16];
#pragma unroll
  for (int f = 0; f < 2; ++f) {
#pragma unroll
    for (int g = 0; g < 4; ++g)
#pragma unroll
      for (int r = 0; r < 4; ++r)
        mytr[((lane >> 4) * 4 + r) * 68 + g * 16 + (lane & 15)] = acc[f][g][r];
    int tl = h * 32 + f * 16 + lr;
    int R = blk * 64 + tl;
    size_t base = ((size_t)(R >> 4) * 8 + (colL >> 5)) * 512;
    int q0 = (colL & 31) >> 3;
    HF8 rh0, rh1, rl0, rl1;
    rh0.v = ldh8(&Rh[base + (q0 * 16 + lr) * 8]);
    rh1.v = ldh8(&Rh[base + ((q0 + 1) * 16 + lr) * 8]);
    rl0.v = ldh8(&Rl[base + (q0 * 16 + lr) * 8]);
    rl1.v = ldh8(&Rl[base + ((q0 + 1) * 16 + lr) * 8]);
    float s1 = 0.f, s2 = 0.f;
#pragma unroll
    for (int i = 0; i < 4; ++i) {
      float4 t = *(const float4*)&mytr[lr * 68 + cb + i * 4];
      float4 bb = *(const float4*)&mgb[colL + i * 4];
      float tv[4] = {t.x + bb.x, t.y + bb.y, t.z + bb.z, t.w + bb.w};
#pragma unroll
      for (int q2 = 0; q2 < 4; ++q2) {
        int ii = i * 4 + q2;
        float rv = (ii < 8) ? h2f(rh0.u[ii]) + h2f(rl0.u[ii])
                            : h2f(rh1.u[ii - 8]) + h2f(rl1.u[ii - 8]);
        float v = tv[q2] + rv;
        y[f][ii] = v; s1 += v; s2 += v * v;
      }
    }
    s1 += __shfl_xor(s1, 1, 64); s2 += __shfl_xor(s2, 1, 64);
    s1 += __shfl_xor(s1, 2, 64); s2 += __shfl_xor(s2, 2, 64);
    if ((lane & 3) == 0) { st[tl * 8 + c * 2] = s1; st[tl * 8 + c * 2 + 1] = s2; }
  }
  __syncthreads();
#pragma unroll
  for (int f = 0; f < 2; ++f) {
    int tl = h * 32 + f * 16 + lr;
    int R = blk * 64 + tl;
    float s1 = st[tl * 8] + st[tl * 8 + 2] + st[tl * 8 + 4] + st[tl * 8 + 6];
    float s2 = st[tl * 8 + 1] + st[tl * 8 + 3] + st[tl * 8 + 5] + st[tl * 8 + 7];
    float mu = s1 * (1.f / 256.f);
    float rs = rsqrtf(s2 * (1.f / 256.f) - mu * mu + 1e-5f);
    HF8 h0, l0, h1, l1;
    float t1 = 0.f, t2 = 0.f;
#pragma unroll
    for (int i = 0; i < 16; ++i) {
      float x = (y[f][i] - mu) * rs * nmw[colL + i] + nmb[colL + i];
      y[f][i] = x; t1 += x; t2 += x * x;
      ushort hh, ll; split_h(x, hh, ll);
      if (i < 8) { h0.u[i] = hh; l0.u[i] = ll; } else { h1.u[i - 8] = hh; l1.u[i - 8] = ll; }
    }
    size_t base = ((size_t)(R >> 4) * 8 + (colL >> 5)) * 512;
    int q0 = (colL & 31) >> 3;
    *(f16x8*)&Xch[base + (q0 * 16 + lr) * 8] = h0.v;
    *(f16x8*)&Xch[base + ((q0 + 1) * 16 + lr) * 8] = h1.v;
    *(f16x8*)&Xcl[base + (q0 * 16 + lr) * 8] = l0.v;
    *(f16x8*)&Xcl[base + ((q0 + 1) * 16 + lr) * 8] = l1.v;
    t1 += __shfl_xor(t1, 1, 64); t2 += __shfl_xor(t2, 1, 64);
    t1 += __shfl_xor(t1, 2, 64); t2 += __shfl_xor(t2, 2, 64);
    if ((lane & 3) == 0) { stB[tl * 8 + c * 2] = t1; stB[tl * 8 + c * 2 + 1] = t2; }
  }
  __syncthreads();
#pragma unroll
  for (int f = 0; f < 2; ++f) {
    int tl = h * 32 + f * 16 + lr;
    int R = blk * 64 + tl;
    float s1 = stB[tl * 8] + stB[tl * 8 + 2] + stB[tl * 8 + 4] + stB[tl * 8 + 6];
    float s2 = stB[tl * 8 + 1] + stB[tl * 8 + 3] + stB[tl * 8 + 5] + stB[tl * 8 + 7];
    float mu = s1 * (1.f / 256.f);
    float rs = rsqrtf(s2 * (1.f / 256.f) - mu * mu + 1e-5f);
    HF8 h0, h1;
#pragma unroll
    for (int i = 0; i < 16; ++i) {
      float z = (y[f][i] - mu) * rs * fw[colL + i] + fb[colL + i];
      if (i < 8) h0.u[i] = f2h(z); else h1.u[i - 8] = f2h(z);
    }
    size_t base = ((size_t)(R >> 4) * 8 + (colL >> 5)) * 512;
    int q0 = (colL & 31) >> 3;
    *(f16x8*)&Hbh[base + (q0 * 16 + lr) * 8] = h0.v;
    *(f16x8*)&Hbh[base + ((q0 + 1) * 16 + lr) * 8] = h1.v;
  }
}

// ---------------------------------------------------------------------------
// KC: out = (Xc + gelu(Hb @ W1 + b1) @ W2 + b2) * mask. 64 tok/block,
// 8 phases x 2 slabs; A persistent in regs (kt fully unrolled).
// ---------------------------------------------------------------------------
template<bool FINAL>
__global__ __launch_bounds__(512) void k_ffn(
    const ushort* __restrict__ Hbh,
    const ushort* __restrict__ W1h, const ushort* __restrict__ W1l,
    const float* __restrict__ b1,
    const ushort* __restrict__ W2h, const ushort* __restrict__ W2l,
    const float* __restrict__ b2,
    const ushort* __restrict__ Xch, const ushort* __restrict__ Xcl,
    const float* __restrict__ keep,
    float* __restrict__ outf, ushort* __restrict__ Oh, ushort* __restrict__ Ol) {
  __shared__ __align__(16) char lraw[36864];
  ushort* Hs16 = (ushort*)lraw;  // [2 dbuf][2 slab][4096] = 32KB
  float* trw = (float*)lraw;     // epilogue alias

  const int tid = threadIdx.x, lane = tid & 63, w = tid >> 6;
  const int h = w >> 2, c = w & 3;
  const int blk = blockIdx.x;

  f16x8 Areg[2][8];
#pragma unroll
  for (int f = 0; f < 2; ++f)
#pragma unroll
    for (int kt = 0; kt < 8; ++kt)
      Areg[f][kt] = ldh8(&Hbh[((size_t)(blk * 4 + h * 2 + f) * 8 + kt) * 512 + lane * 8]);

  f32x4 acc[2][4];
#pragma unroll
  for (int f = 0; f < 2; ++f)
#pragma unroll
    for (int g = 0; g < 4; ++g) acc[f][g] = (f32x4){0.f, 0.f, 0.f, 0.f};

  auto gemm1p = [&](int p, f32x4 a1[2][2]) {
#pragma unroll
    for (int kt = 0; kt < 8; ++kt) {
#pragma unroll
      for (int sl = 0; sl < 2; ++sl) {
        int s = p * 2 + sl;
        size_t wt = ((size_t)(s * 4 + c) * 8 + kt) * 512 + lane * 8;
        f16x8 bh = ldh8(&W1h[wt]), bl = ldh8(&W1l[wt]);
#pragma unroll
        for (int f = 0; f < 2; ++f) {
          a1[sl][f] = MFMA16(Areg[f][kt], bh, a1[sl][f]);
          a1[sl][f] = MFMA16(Areg[f][kt], bl, a1[sl][f]);
        }
      }
    }
  };
  auto hswrp = [&](int p, f32x4 a1[2][2]) {
    const int ktile = c >> 1;
    const int q = (c & 1) * 2 + ((lane & 15) >> 3);
    const int e = lane & 7;
#pragma unroll
    for (int sl = 0; sl < 2; ++sl) {
      int s = p * 2 + sl;
      ushort* dst = Hs16 + (p & 1) * 8192 + sl * 4096;
      const float bias1 = b1[s * 64 + c * 16 + (lane & 15)];
#pragma unroll
      for (int f = 0; f < 2; ++f) {
        const int rt = h * 2 + f;
#pragma unroll
        for (int r = 0; r < 4; ++r) {
          float x = gelu_f(a1[sl][f][r] + bias1);
          int t16 = (lane >> 4) * 4 + r;
          int idx = ((q * 16 + t16) * 8 + e) ^ (((t16 >> 2) & 3) * 8);
          dst[(rt * 2 + ktile) * 512 + idx] = f2h(x);
        }
      }
    }
  };

  {
    f32x4 a1[2][2] = {};
    gemm1p(0, a1); hswrp(0, a1);
  }
#pragma unroll 1
  for (int p = 0; p < 8; ++p) {
    lgkm_barrier();
    const ushort* src = Hs16 + (p & 1) * 8192;
#pragma unroll
    for (int sl = 0; sl < 2; ++sl) {
      int s = p * 2 + sl;
#pragma unroll
      for (int ks = 0; ks < 2; ++ks) {
        f16x8 hh2[2];
#pragma unroll
        for (int f = 0; f < 2; ++f)
          hh2[f] = rdtile16(src, sl * 8 + (h * 2 + f) * 2 + ks, lane);
#pragma unroll
        for (int g = 0; g < 4; ++g) {
          size_t wt = ((size_t)(c * 4 + g) * 32 + (s * 2 + ks)) * 512 + lane * 8;
          f16x8 bh = ldh8(&W2h[wt]), bl = ldh8(&W2l[wt]);
#pragma unroll
          for (int f = 0; f < 2; ++f) {
            acc[f][g] = MFMA16(hh2[f], bh, acc[f][g]);
            acc[f][g] = MFMA16(hh2[f], bl, acc[f][g]);
          }
        }
      }
    }
    if (p < 7) {
      f32x4 a1[2][2] = {};
      gemm1p(p + 1, a1); hswrp(p + 1, a1);
    }
  }
  __syncthreads();

  float* mytr = trw + w * 1088;
  const int lr = lane >> 2, cb = (lane & 3) * 16;
  const int colL = c * 64 + cb;
#pragma unroll
  for (int f = 0; f < 2; ++f) {
#pragma unroll
    for (int g = 0; g < 4; ++g)
#pragma unroll
      for (int r = 0; r < 4; ++r)
        mytr[((lane >> 4) * 4 + r) * 68 + g * 16 + (lane & 15)] = acc[f][g][r];
    int tl = h * 32 + f * 16 + lr;
    int R = blk * 64 + tl;
    float mk = keep[R];
    size_t base = ((size_t)(R >> 4) * 8 + (colL >> 5)) * 512;
    int q0 = (colL & 31) >> 3;
    HF8 rh0, rh1, rl0, rl1;
    rh0.v = ldh8(&Xch[base + (q0 * 16 + lr) * 8]);
    rh1.v = ldh8(&Xch[base + ((q0 + 1) * 16 + lr) * 8]);
    rl0.v = ldh8(&Xcl[base + (q0 * 16 + lr) * 8]);
    rl1.v = ldh8(&Xcl[base + ((q0 + 1) * 16 + lr) * 8]);
    float z[16];
#pragma unroll
    for (int i = 0; i < 4; ++i) {
      float4 t = *(const float4*)&mytr[lr * 68 + cb + i * 4];
      float4 bb = *(const float4*)&b2[colL + i * 4];
      float tv[4] = {t.x + bb.x, t.y + bb.y, t.z + bb.z, t.w + bb.w};
#pragma unroll
      for (int q2 = 0; q2 < 4; ++q2) {
        int ii = i * 4 + q2;
        float rv = (ii < 8) ? h2f(rh0.u[ii]) + h2f(rl0.u[ii])
                            : h2f(rh1.u[ii - 8]) + h2f(rl1.u[ii - 8]);
        z[ii] = (rv + tv[q2]) * mk;
      }
    }
    if (FINAL) {
#pragma unroll
      for (int i = 0; i < 4; ++i)
        *(float4*)&outf[(size_t)R * 256 + colL + i * 4] = *(const float4*)&z[i * 4];
    } else {
      HF8 h0, l0, h1, l1;
#pragma unroll
      for (int i = 0; i < 16; ++i) {
        ushort hh, ll; split_h(z[i], hh, ll);
        if (i < 8) { h0.u[i] = hh; l0.u[i] = ll; } else { h1.u[i - 8] = hh; l1.u[i - 8] = ll; }
      }
      *(f16x8*)&Oh[base + (q0 * 16 + lr) * 8] = h0.v;
      *(f16x8*)&Oh[base + ((q0 + 1) * 16 + lr) * 8] = h1.v;
      *(f16x8*)&Ol[base + (q0 * 16 + lr) * 8] = l0.v;
      *(f16x8*)&Ol[base + ((q0 + 1) * 16 + lr) * 8] = l1.v;
    }
  }
}

// X fp32 [rows][256] -> A-frag fp16 hl (nkt=8)
__global__ __launch_bounds__(256) void k_xprep(const float* __restrict__ X,
    ushort* __restrict__ Dh, ushort* __restrict__ Dl) {
  int t = blockIdx.x * 4 + (threadIdx.x >> 6);
  int lane = threadIdx.x & 63;
  int rt = t >> 3, kt = t & 7;
  const float* sp = X + (size_t)(rt * 16 + (lane & 15)) * 256 + kt * 32 + (lane >> 4) * 8;
  float4 a = *(const float4*)sp;
  float4 b = *(const float4*)(sp + 4);
  float xs[8] = {a.x, a.y, a.z, a.w, b.x, b.y, b.z, b.w};
  HF8 h, l;
#pragma unroll
  for (int e = 0; e < 8; ++e) split_h(xs[e], h.u[e], l.u[e]);
  *(f16x8*)&Dh[(size_t)t * 512 + lane * 8] = h.v;
  *(f16x8*)&Dl[(size_t)t * 512 + lane * 8] = l.v;
}

// W fp32 [K][Nout] -> B-frag fp16 hl [Nout/16][K/32]
__global__ __launch_bounds__(256) void k_wprep(const float* __restrict__ W,
    ushort* __restrict__ Dh, ushort* __restrict__ Dl, int Nout, int K) {
  int t = blockIdx.x * 4 + (threadIdx.x >> 6);
  int lane = threadIdx.x & 63;
  int nkt = K >> 5;
  int nt = t / nkt, kt = t % nkt;
  int n = nt * 16 + (lane & 15);
  int k0 = kt * 32 + (lane >> 4) * 8;
  HF8 h, l;
#pragma unroll
  for (int e = 0; e < 8; ++e) {
    float x = W[(size_t)(k0 + e) * Nout + n];
    split_h(x, h.u[e], l.u[e]);
  }
  *(f16x8*)&Dh[(size_t)t * 512 + lane * 8] = h.v;
  *(f16x8*)&Dl[(size_t)t * 512 + lane * 8] = l.v;
}

extern "C" void kernel_launch(void* const* d_in, const int* in_sizes, int n_in,
                              void* d_out, int out_size, void* d_ws, size_t ws_size,
                              hipStream_t stream) {
  const float* slots  = (const float*)d_in[0];
  const float* keep   = (const float*)d_in[1];
  const float* fw_w1  = (const float*)d_in[2];
  const float* fw_b1  = (const float*)d_in[3];
  const float* fw_w2  = (const float*)d_in[4];
  const float* fw_b2  = (const float*)d_in[5];
  const float* fw_lnw = (const float*)d_in[6];
  const float* fw_lnb = (const float*)d_in[7];
  const float* bw_w1  = (const float*)d_in[8];
  const float* bw_b1  = (const float*)d_in[9];
  const float* bw_w2  = (const float*)d_in[10];
  const float* bw_b2  = (const float*)d_in[11];
  const float* bw_lnw = (const float*)d_in[12];
  const float* bw_lnb = (const float*)d_in[13];
  const float* mg_w   = (const float*)d_in[14];
  const float* mg_b   = (const float*)d_in[15];
  const float* nm_w   = (const float*)d_in[16];
  const float* nm_b   = (const float*)d_in[17];
  const float* ffn_lnw= (const float*)d_in[18];
  const float* ffn_lnb= (const float*)d_in[19];
  const float* ffn_w1 = (const float*)d_in[20];
  const float* ffn_b1 = (const float*)d_in[21];
  const float* ffn_w2 = (const float*)d_in[22];
  const float* ffn_b2 = (const float*)d_in[23];
  (void)n_in; (void)out_size;

  const int N = in_sizes[0] / 256;
  float* out = (float*)d_out;

  size_t off = 0;
  char* wsb = (char*)d_ws;
  auto allocU = [&](size_t elems) -> ushort* {
    void* p = wsb + off;
    off = (off + elems * 2 + 255) & ~(size_t)255;
    return (ushort*)p;
  };

  struct LayerW {
    ushort *fw1h, *fw1l, *bw1h, *bw1l, *fw2h, *fw2l, *bw2h, *bw2l;
    ushort *mgh, *mgl, *f1h, *f1l, *f2h, *f2l;
  } lw[2];
  for (int L = 0; L < 2; ++L) {
    lw[L].fw1h = allocU(131072); lw[L].fw1l = allocU(131072);
    lw[L].bw1h = allocU(131072); lw[L].bw1l = allocU(131072);
    lw[L].fw2h = allocU(131072); lw[L].fw2l = allocU(131072);
    lw[L].bw2h = allocU(131072); lw[L].bw2l = allocU(131072);
    lw[L].mgh  = allocU(131072); lw[L].mgl  = allocU(131072);
    lw[L].f1h  = allocU(262144); lw[L].f1l  = allocU(262144);
    lw[L].f2h  = allocU(262144); lw[L].f2l  = allocU(262144);
  }

  size_t remain = ws_size > off + 4096 ? ws_size - off - 4096 : 0;
  int chunk = N;
  while ((size_t)chunk * 4608 > remain && chunk > 512) chunk >>= 1;

  ushort* Xfh = allocU((size_t)chunk * 256); ushort* Xfl = allocU((size_t)chunk * 256);
  ushort* Fh  = allocU((size_t)chunk * 512);
  ushort* Xch = allocU((size_t)chunk * 256); ushort* Xcl = allocU((size_t)chunk * 256);
  ushort* Hbh = allocU((size_t)chunk * 256);
  ushort* X2h = allocU((size_t)chunk * 256); ushort* X2l = allocU((size_t)chunk * 256);

  for (int L = 0; L < 2; ++L) {
    k_wprep<<<64, 256, 0, stream>>>(fw_w1 + (size_t)L * 131072, lw[L].fw1h, lw[L].fw1l, 512, 256);
    k_wprep<<<64, 256, 0, stream>>>(bw_w1 + (size_t)L * 131072, lw[L].bw1h, lw[L].bw1l, 512, 256);
    k_wprep<<<64, 256, 0, stream>>>(fw_w2 + (size_t)L * 131072, lw[L].fw2h, lw[L].fw2l, 256, 512);
    k_wprep<<<64, 256, 0, stream>>>(bw_w2 + (size_t)L * 131072, lw[L].bw2h, lw[L].bw2l, 256, 512);
    k_wprep<<<64, 256, 0, stream>>>(mg_w + (size_t)L * 131072, lw[L].mgh, lw[L].mgl, 256, 512);
    k_wprep<<<128, 256, 0, stream>>>(ffn_w1 + (size_t)L * 262144, lw[L].f1h, lw[L].f1l, 1024, 256);
    k_wprep<<<128, 256, 0, stream>>>(ffn_w2 + (size_t)L * 262144, lw[L].f2h, lw[L].f2l, 256, 1024);
  }

  for (int c0 = 0; c0 < N; c0 += chunk) {
    k_xprep<<<(chunk / 16) * 2, 256, 0, stream>>>(slots + (size_t)c0 * 256, Xfh, Xfl);
    const int gx = chunk / 64;
    for (int L = 0; L < 2; ++L) {
      const ushort* Xh = (L == 0) ? Xfh : X2h;
      const ushort* Xl = (L == 0) ? Xfl : X2l;
      k_lin12<<<dim3(gx, 2), 512, 0, stream>>>(
          Xh,
          lw[L].fw1h, lw[L].fw1l, lw[L].bw1h, lw[L].bw1l,
          lw[L].fw2h, lw[L].fw2l, lw[L].bw2h, lw[L].bw2l,
          fw_b1 + (size_t)L * 512, bw_b1 + (size_t)L * 512,
          fw_b2 + (size_t)L * 256, bw_b2 + (size_t)L * 256,
          fw_lnw + (size_t)L * 256, fw_lnb + (size_t)L * 256,
          bw_lnw + (size_t)L * 256, bw_lnb + (size_t)L * 256,
          Fh);
      k_mergep<<<gx, 512, 0, stream>>>(
          Fh, lw[L].mgh, lw[L].mgl, mg_b + (size_t)L * 256,
          Xh, Xl,
          nm_w + (size_t)L * 256, nm_b + (size_t)L * 256,
          ffn_lnw + (size_t)L * 256, ffn_lnb + (size_t)L * 256,
          Xch, Xcl, Hbh);
      if (L == 0) {
        k_ffn<false><<<gx, 512, 0, stream>>>(
            Hbh, lw[L].f1h, lw[L].f1l, ffn_b1 + (size_t)L * 1024,
            lw[L].f2h, lw[L].f2l, ffn_b2 + (size_t)L * 256,
            Xch, Xcl, keep + c0, nullptr, X2h, X2l);
      } else {
        k_ffn<true><<<gx, 512, 0, stream>>>(
            Hbh, lw[L].f1h, lw[L].f1l, ffn_b1 + (size_t)L * 1024,
            lw[L].f2h, lw[L].f2l, ffn_b2 + (size_t)L * 256,
            Xch, Xcl, keep + c0, out + (size_t)c0 * 256, nullptr, nullptr);
      }
    }
  }
}

// Round 19
// 2208.868 us; speedup vs baseline: 1.4869x; 1.4869x over previous
//
#include <hip/hip_runtime.h>
#include <math.h>
#include <stdint.h>

typedef _Float16 f16x8 __attribute__((ext_vector_type(8)));
typedef __attribute__((ext_vector_type(4))) float f32x4;

#define MFMA16(a, b, c) __builtin_amdgcn_mfma_f32_16x16x32_f16(a, b, c, 0, 0, 0)

union H16 { _Float16 f; ushort u; };
union HF8 { ushort u[8]; f16x8 v; };

__device__ __forceinline__ ushort f2h(float x) { H16 t; t.f = (_Float16)x; return t.u; }
__device__ __forceinline__ float h2f(ushort u) { H16 t; t.u = u; return (float)t.f; }
__device__ __forceinline__ void split_h(float x, ushort& h, ushort& l) {
  h = f2h(x);
  l = f2h(x - h2f(h));
}
__device__ __forceinline__ f16x8 ldh8(const ushort* p) { return *(const f16x8*)p; }

__device__ __forceinline__ float silu_f(float x) {
  float e = __builtin_amdgcn_exp2f(x * -1.44269504089f);
  return x * __builtin_amdgcn_rcpf(1.f + e);
}
__device__ __forceinline__ float gelu_f(float x) {
  float z = fabsf(x) * 0.70710678118654752f;
  float t = __builtin_amdgcn_rcpf(fmaf(0.3275911f, z, 1.f));
  float poly = t * (0.254829592f + t * (-0.284496736f + t * (1.421413741f +
               t * (-1.453152027f + t * 1.061405429f))));
  float e = __builtin_amdgcn_exp2f(-z * z * 1.44269504089f);
  float erfz = copysignf(1.f - poly * e, x);
  return 0.5f * x * (1.f + erfz);
}

// write-drain barrier: LDS writes visible, global loads stay in flight
__device__ __forceinline__ void lgkm_barrier() {
  asm volatile("s_waitcnt lgkmcnt(0)" ::: "memory");
  __builtin_amdgcn_s_barrier();
}

// Fragment-linear: buffer[rt][kt][lane][8] ushorts (tile=512).
// A-frag: lane holds row lane&15, k=kt*32+(lane>>4)*8+e.
// C-frag [m89]: col=lane&15(+g*16), row=(lane>>4)*4+r(+f*16).
// LDS hand-off: single fp16 plane, 512 ushorts/tile, XOR swizzle:
//   idx = ((q*16+t)*8+e) ^ (((t>>2)&3)*8); read b128 at (lane*8)^swz.

__device__ __forceinline__ f16x8 rdtile16(const ushort* src, int T, int lane) {
  int idx = T * 512 + ((lane * 8) ^ (((lane >> 2) & 3) * 8));
  return *(const f16x8*)&src[idx];
}

// ---------------------------------------------------------------------------
// KA: F_br = LN_br(silu(X @ W1b + b1) @ W2b + b2).  64 tok/block, branch =
// blockIdx.y. 4 phases x 2 slabs (r15-proven structure) + T5 setprio around
// GEMM2 MFMA cluster.
// ---------------------------------------------------------------------------
__global__ __launch_bounds__(512) void k_lin12(
    const ushort* __restrict__ Xh,
    const ushort* __restrict__ fW1h, const ushort* __restrict__ fW1l,
    const ushort* __restrict__ bW1h, const ushort* __restrict__ bW1l,
    const ushort* __restrict__ fW2h, const ushort* __restrict__ fW2l,
    const ushort* __restrict__ bW2h, const ushort* __restrict__ bW2l,
    const float* __restrict__ fb1, const float* __restrict__ bb1,
    const float* __restrict__ fb2, const float* __restrict__ bb2,
    const float* __restrict__ flw, const float* __restrict__ flb,
    const float* __restrict__ blw, const float* __restrict__ blb,
    ushort* __restrict__ Fh) {
  __shared__ __align__(16) char lraw[36864];
  __shared__ float st[512];
  ushort* Hs16 = (ushort*)lraw;  // [2 dbuf][2 slab][4096] ushorts = 32KB
  float* trw = (float*)lraw;     // [8][1088] (epilogue alias)

  const int tid = threadIdx.x, lane = tid & 63, w = tid >> 6;
  const int h = w >> 2, c = w & 3;
  const int blk = blockIdx.x, br = blockIdx.y;
  const ushort* W1h = br ? bW1h : fW1h; const ushort* W1l = br ? bW1l : fW1l;
  const ushort* W2h = br ? bW2h : fW2h; const ushort* W2l = br ? bW2l : fW2l;
  const float* b1 = br ? bb1 : fb1;
  const float* b2 = br ? bb2 : fb2;
  const float* lw = br ? blw : flw;
  const float* lb = br ? blb : flb;

  f32x4 acc[2][4];
#pragma unroll
  for (int f = 0; f < 2; ++f)
#pragma unroll
    for (int g = 0; g < 4; ++g) acc[f][g] = (f32x4){0.f, 0.f, 0.f, 0.f};

  // gemm1 for a phase: both slabs (2p, 2p+1); A loaded once per kt.
  auto gemm1p = [&](int p, f32x4 a1[2][2]) {
#pragma unroll 4
    for (int kt = 0; kt < 8; ++kt) {
      f16x8 ah[2];
#pragma unroll
      for (int f = 0; f < 2; ++f) {
        size_t at = ((size_t)(blk * 4 + h * 2 + f) * 8 + kt) * 512 + lane * 8;
        ah[f] = ldh8(&Xh[at]);
      }
#pragma unroll
      for (int sl = 0; sl < 2; ++sl) {
        int s = p * 2 + sl;
        size_t wt = ((size_t)(s * 4 + c) * 8 + kt) * 512 + lane * 8;
        f16x8 bh = ldh8(&W1h[wt]), bl = ldh8(&W1l[wt]);
#pragma unroll
        for (int f = 0; f < 2; ++f) {
          a1[sl][f] = MFMA16(ah[f], bh, a1[sl][f]);
          a1[sl][f] = MFMA16(ah[f], bl, a1[sl][f]);
        }
      }
    }
  };
  auto hswrp = [&](int p, f32x4 a1[2][2]) {
    const int ktile = c >> 1;
    const int q = (c & 1) * 2 + ((lane & 15) >> 3);
    const int e = lane & 7;
#pragma unroll
    for (int sl = 0; sl < 2; ++sl) {
      int s = p * 2 + sl;
      ushort* dst = Hs16 + (p & 1) * 8192 + sl * 4096;
      const float bias1 = b1[s * 64 + c * 16 + (lane & 15)];
#pragma unroll
      for (int f = 0; f < 2; ++f) {
        const int rt = h * 2 + f;
#pragma unroll
        for (int r = 0; r < 4; ++r) {
          float x = silu_f(a1[sl][f][r] + bias1);
          int t16 = (lane >> 4) * 4 + r;
          int idx = ((q * 16 + t16) * 8 + e) ^ (((t16 >> 2) & 3) * 8);
          dst[(rt * 2 + ktile) * 512 + idx] = f2h(x);
        }
      }
    }
  };

  {
    f32x4 a1[2][2] = {};
    gemm1p(0, a1); hswrp(0, a1);
  }
#pragma unroll 1
  for (int p = 0; p < 4; ++p) {
    lgkm_barrier();
    const ushort* src = Hs16 + (p & 1) * 8192;
    __builtin_amdgcn_s_setprio(1);
#pragma unroll
    for (int sl = 0; sl < 2; ++sl) {
      int s = p * 2 + sl;
#pragma unroll
      for (int ks = 0; ks < 2; ++ks) {
        f16x8 hh2[2];
#pragma unroll
        for (int f = 0; f < 2; ++f)
          hh2[f] = rdtile16(src, sl * 8 + (h * 2 + f) * 2 + ks, lane);
#pragma unroll
        for (int g = 0; g < 4; ++g) {
          size_t wt = ((size_t)(c * 4 + g) * 16 + (s * 2 + ks)) * 512 + lane * 8;
          f16x8 bh = ldh8(&W2h[wt]), bl = ldh8(&W2l[wt]);
#pragma unroll
          for (int f = 0; f < 2; ++f) {
            acc[f][g] = MFMA16(hh2[f], bh, acc[f][g]);
            acc[f][g] = MFMA16(hh2[f], bl, acc[f][g]);
          }
        }
      }
    }
    __builtin_amdgcn_s_setprio(0);
    if (p < 3) {
      f32x4 a1[2][2] = {};
      gemm1p(p + 1, a1); hswrp(p + 1, a1);
    }
  }
  __syncthreads();  // all Hs reads done; trw aliases the region

  // epilogue: bias2 + branch LN; coalesced via per-wave padded transpose
  float* mytr = trw + w * 1088;
  const int lr = lane >> 2, cb = (lane & 3) * 16;
  const int colL = c * 64 + cb;
  float y[2][16];
#pragma unroll
  for (int f = 0; f < 2; ++f) {
#pragma unroll
    for (int g = 0; g < 4; ++g)
#pragma unroll
      for (int r = 0; r < 4; ++r)
        mytr[((lane >> 4) * 4 + r) * 68 + g * 16 + (lane & 15)] = acc[f][g][r];
    float s1 = 0.f, s2 = 0.f;
#pragma unroll
    for (int i = 0; i < 4; ++i) {
      float4 t = *(const float4*)&mytr[lr * 68 + cb + i * 4];
      float4 bb = *(const float4*)&b2[colL + i * 4];
      y[f][i * 4 + 0] = t.x + bb.x; y[f][i * 4 + 1] = t.y + bb.y;
      y[f][i * 4 + 2] = t.z + bb.z; y[f][i * 4 + 3] = t.w + bb.w;
#pragma unroll
      for (int q2 = 0; q2 < 4; ++q2) { float v = y[f][i * 4 + q2]; s1 += v; s2 += v * v; }
    }
    s1 += __shfl_xor(s1, 1, 64); s2 += __shfl_xor(s2, 1, 64);
    s1 += __shfl_xor(s1, 2, 64); s2 += __shfl_xor(s2, 2, 64);
    if ((lane & 3) == 0) {
      int tl = h * 32 + f * 16 + lr;
      st[tl * 8 + c * 2] = s1; st[tl * 8 + c * 2 + 1] = s2;
    }
  }
  lgkm_barrier();
#pragma unroll
  for (int f = 0; f < 2; ++f) {
    int tl = h * 32 + f * 16 + lr;
    float s1 = st[tl * 8] + st[tl * 8 + 2] + st[tl * 8 + 4] + st[tl * 8 + 6];
    float s2 = st[tl * 8 + 1] + st[tl * 8 + 3] + st[tl * 8 + 5] + st[tl * 8 + 7];
    float mu = s1 * (1.f / 256.f);
    float rs = rsqrtf(s2 * (1.f / 256.f) - mu * mu + 1e-5f);
    HF8 h0, h1;
#pragma unroll
    for (int i = 0; i < 16; ++i) {
      float z = (y[f][i] - mu) * rs * lw[colL + i] + lb[colL + i];
      if (i < 8) h0.u[i] = f2h(z); else h1.u[i - 8] = f2h(z);
    }
    int R = blk * 64 + tl;
    int Cg = br * 256 + colL;
    size_t base = ((size_t)(R >> 4) * 16 + (Cg >> 5)) * 512;
    int q0 = (Cg & 31) >> 3;
    *(f16x8*)&Fh[base + (q0 * 16 + lr) * 8] = h0.v;
    *(f16x8*)&Fh[base + ((q0 + 1) * 16 + lr) * 8] = h1.v;
  }
}

// ---------------------------------------------------------------------------
// KB: M = F @ mg + b; Xc = LN(resid + M, nm); Hb = LN(Xc, ffn).
// ---------------------------------------------------------------------------
__global__ __launch_bounds__(512) void k_mergep(
    const ushort* __restrict__ Fh,
    const ushort* __restrict__ Mh, const ushort* __restrict__ Ml,
    const float* __restrict__ mgb,
    const ushort* __restrict__ Rh, const ushort* __restrict__ Rl,
    const float* __restrict__ nmw, const float* __restrict__ nmb,
    const float* __restrict__ fw, const float* __restrict__ fb,
    ushort* __restrict__ Xch, ushort* __restrict__ Xcl,
    ushort* __restrict__ Hbh) {
  __shared__ float trw[8][1088];
  __shared__ float st[512], stB[512];
  const int tid = threadIdx.x, lane = tid & 63, w = tid >> 6;
  const int h = w >> 2, c = w & 3;
  const int blk = blockIdx.x;

  f32x4 acc[2][4];
#pragma unroll
  for (int f = 0; f < 2; ++f)
#pragma unroll
    for (int g = 0; g < 4; ++g) acc[f][g] = (f32x4){0.f, 0.f, 0.f, 0.f};

#pragma unroll 2
  for (int kt = 0; kt < 16; ++kt) {
    f16x8 ah[2];
#pragma unroll
    for (int f = 0; f < 2; ++f) {
      size_t at = ((size_t)(blk * 4 + h * 2 + f) * 16 + kt) * 512 + lane * 8;
      ah[f] = ldh8(&Fh[at]);
    }
#pragma unroll
    for (int g = 0; g < 4; ++g) {
      size_t wt = ((size_t)(c * 4 + g) * 16 + kt) * 512 + lane * 8;
      f16x8 bh = ldh8(&Mh[wt]), bl = ldh8(&Ml[wt]);
#pragma unroll
      for (int f = 0; f < 2; ++f) {
        acc[f][g] = MFMA16(ah[f], bh, acc[f][g]);
        acc[f][g] = MFMA16(ah[f], bl, acc[f][g]);
      }
    }
  }

  float* mytr = &trw[w][0];
  const int lr = lane >> 2, cb = (lane & 3) * 16;
  const int colL = c * 64 + cb;
  float y[2][16];
#pragma unroll
  for (int f = 0; f < 2; ++f) {
#pragma unroll
    for (int g = 0; g < 4; ++g)
#pragma unroll
      for (int r = 0; r < 4; ++r)
        mytr[((lane >> 4) * 4 + r) * 68 + g * 16 + (lane & 15)] = acc[f][g][r];
    int tl = h * 32 + f * 16 + lr;
    int R = blk * 64 + tl;
    size_t base = ((size_t)(R >> 4) * 8 + (colL >> 5)) * 512;
    int q0 = (colL & 31) >> 3;
    HF8 rh0, rh1, rl0, rl1;
    rh0.v = ldh8(&Rh[base + (q0 * 16 + lr) * 8]);
    rh1.v = ldh8(&Rh[base + ((q0 + 1) * 16 + lr) * 8]);
    rl0.v = ldh8(&Rl[base + (q0 * 16 + lr) * 8]);
    rl1.v = ldh8(&Rl[base + ((q0 + 1) * 16 + lr) * 8]);
    float s1 = 0.f, s2 = 0.f;
#pragma unroll
    for (int i = 0; i < 4; ++i) {
      float4 t = *(const float4*)&mytr[lr * 68 + cb + i * 4];
      float4 bb = *(const float4*)&mgb[colL + i * 4];
      float tv[4] = {t.x + bb.x, t.y + bb.y, t.z + bb.z, t.w + bb.w};
#pragma unroll
      for (int q2 = 0; q2 < 4; ++q2) {
        int ii = i * 4 + q2;
        float rv = (ii < 8) ? h2f(rh0.u[ii]) + h2f(rl0.u[ii])
                            : h2f(rh1.u[ii - 8]) + h2f(rl1.u[ii - 8]);
        float v = tv[q2] + rv;
        y[f][ii] = v; s1 += v; s2 += v * v;
      }
    }
    s1 += __shfl_xor(s1, 1, 64); s2 += __shfl_xor(s2, 1, 64);
    s1 += __shfl_xor(s1, 2, 64); s2 += __shfl_xor(s2, 2, 64);
    if ((lane & 3) == 0) { st[tl * 8 + c * 2] = s1; st[tl * 8 + c * 2 + 1] = s2; }
  }
  __syncthreads();
#pragma unroll
  for (int f = 0; f < 2; ++f) {
    int tl = h * 32 + f * 16 + lr;
    int R = blk * 64 + tl;
    float s1 = st[tl * 8] + st[tl * 8 + 2] + st[tl * 8 + 4] + st[tl * 8 + 6];
    float s2 = st[tl * 8 + 1] + st[tl * 8 + 3] + st[tl * 8 + 5] + st[tl * 8 + 7];
    float mu = s1 * (1.f / 256.f);
    float rs = rsqrtf(s2 * (1.f / 256.f) - mu * mu + 1e-5f);
    HF8 h0, l0, h1, l1;
    float t1 = 0.f, t2 = 0.f;
#pragma unroll
    for (int i = 0; i < 16; ++i) {
      float x = (y[f][i] - mu) * rs * nmw[colL + i] + nmb[colL + i];
      y[f][i] = x; t1 += x; t2 += x * x;
      ushort hh, ll; split_h(x, hh, ll);
      if (i < 8) { h0.u[i] = hh; l0.u[i] = ll; } else { h1.u[i - 8] = hh; l1.u[i - 8] = ll; }
    }
    size_t base = ((size_t)(R >> 4) * 8 + (colL >> 5)) * 512;
    int q0 = (colL & 31) >> 3;
    *(f16x8*)&Xch[base + (q0 * 16 + lr) * 8] = h0.v;
    *(f16x8*)&Xch[base + ((q0 + 1) * 16 + lr) * 8] = h1.v;
    *(f16x8*)&Xcl[base + (q0 * 16 + lr) * 8] = l0.v;
    *(f16x8*)&Xcl[base + ((q0 + 1) * 16 + lr) * 8] = l1.v;
    t1 += __shfl_xor(t1, 1, 64); t2 += __shfl_xor(t2, 1, 64);
    t1 += __shfl_xor(t1, 2, 64); t2 += __shfl_xor(t2, 2, 64);
    if ((lane & 3) == 0) { stB[tl * 8 + c * 2] = t1; stB[tl * 8 + c * 2 + 1] = t2; }
  }
  __syncthreads();
#pragma unroll
  for (int f = 0; f < 2; ++f) {
    int tl = h * 32 + f * 16 + lr;
    int R = blk * 64 + tl;
    float s1 = stB[tl * 8] + stB[tl * 8 + 2] + stB[tl * 8 + 4] + stB[tl * 8 + 6];
    float s2 = stB[tl * 8 + 1] + stB[tl * 8 + 3] + stB[tl * 8 + 5] + stB[tl * 8 + 7];
    float mu = s1 * (1.f / 256.f);
    float rs = rsqrtf(s2 * (1.f / 256.f) - mu * mu + 1e-5f);
    HF8 h0, h1;
#pragma unroll
    for (int i = 0; i < 16; ++i) {
      float z = (y[f][i] - mu) * rs * fw[colL + i] + fb[colL + i];
      if (i < 8) h0.u[i] = f2h(z); else h1.u[i - 8] = f2h(z);
    }
    size_t base = ((size_t)(R >> 4) * 8 + (colL >> 5)) * 512;
    int q0 = (colL & 31) >> 3;
    *(f16x8*)&Hbh[base + (q0 * 16 + lr) * 8] = h0.v;
    *(f16x8*)&Hbh[base + ((q0 + 1) * 16 + lr) * 8] = h1.v;
  }
}

// ---------------------------------------------------------------------------
// KC: out = (Xc + gelu(Hb @ W1 + b1) @ W2 + b2) * mask. 64 tok/block,
// 8 phases x 2 slabs (r15-proven) + T5 setprio around GEMM2 MFMA.
// ---------------------------------------------------------------------------
template<bool FINAL>
__global__ __launch_bounds__(512) void k_ffn(
    const ushort* __restrict__ Hbh,
    const ushort* __restrict__ W1h, const ushort* __restrict__ W1l,
    const float* __restrict__ b1,
    const ushort* __restrict__ W2h, const ushort* __restrict__ W2l,
    const float* __restrict__ b2,
    const ushort* __restrict__ Xch, const ushort* __restrict__ Xcl,
    const float* __restrict__ keep,
    float* __restrict__ outf, ushort* __restrict__ Oh, ushort* __restrict__ Ol) {
  __shared__ __align__(16) char lraw[36864];
  ushort* Hs16 = (ushort*)lraw;  // [2 dbuf][2 slab][4096] = 32KB
  float* trw = (float*)lraw;     // epilogue alias

  const int tid = threadIdx.x, lane = tid & 63, w = tid >> 6;
  const int h = w >> 2, c = w & 3;
  const int blk = blockIdx.x;

  f32x4 acc[2][4];
#pragma unroll
  for (int f = 0; f < 2; ++f)
#pragma unroll
    for (int g = 0; g < 4; ++g) acc[f][g] = (f32x4){0.f, 0.f, 0.f, 0.f};

  auto gemm1p = [&](int p, f32x4 a1[2][2]) {
#pragma unroll 4
    for (int kt = 0; kt < 8; ++kt) {
      f16x8 ah[2];
#pragma unroll
      for (int f = 0; f < 2; ++f) {
        size_t at = ((size_t)(blk * 4 + h * 2 + f) * 8 + kt) * 512 + lane * 8;
        ah[f] = ldh8(&Hbh[at]);
      }
#pragma unroll
      for (int sl = 0; sl < 2; ++sl) {
        int s = p * 2 + sl;
        size_t wt = ((size_t)(s * 4 + c) * 8 + kt) * 512 + lane * 8;
        f16x8 bh = ldh8(&W1h[wt]), bl = ldh8(&W1l[wt]);
#pragma unroll
        for (int f = 0; f < 2; ++f) {
          a1[sl][f] = MFMA16(ah[f], bh, a1[sl][f]);
          a1[sl][f] = MFMA16(ah[f], bl, a1[sl][f]);
        }
      }
    }
  };
  auto hswrp = [&](int p, f32x4 a1[2][2]) {
    const int ktile = c >> 1;
    const int q = (c & 1) * 2 + ((lane & 15) >> 3);
    const int e = lane & 7;
#pragma unroll
    for (int sl = 0; sl < 2; ++sl) {
      int s = p * 2 + sl;
      ushort* dst = Hs16 + (p & 1) * 8192 + sl * 4096;
      const float bias1 = b1[s * 64 + c * 16 + (lane & 15)];
#pragma unroll
      for (int f = 0; f < 2; ++f) {
        const int rt = h * 2 + f;
#pragma unroll
        for (int r = 0; r < 4; ++r) {
          float x = gelu_f(a1[sl][f][r] + bias1);
          int t16 = (lane >> 4) * 4 + r;
          int idx = ((q * 16 + t16) * 8 + e) ^ (((t16 >> 2) & 3) * 8);
          dst[(rt * 2 + ktile) * 512 + idx] = f2h(x);
        }
      }
    }
  };

  {
    f32x4 a1[2][2] = {};
    gemm1p(0, a1); hswrp(0, a1);
  }
#pragma unroll 1
  for (int p = 0; p < 8; ++p) {
    lgkm_barrier();
    const ushort* src = Hs16 + (p & 1) * 8192;
    __builtin_amdgcn_s_setprio(1);
#pragma unroll
    for (int sl = 0; sl < 2; ++sl) {
      int s = p * 2 + sl;
#pragma unroll
      for (int ks = 0; ks < 2; ++ks) {
        f16x8 hh2[2];
#pragma unroll
        for (int f = 0; f < 2; ++f)
          hh2[f] = rdtile16(src, sl * 8 + (h * 2 + f) * 2 + ks, lane);
#pragma unroll
        for (int g = 0; g < 4; ++g) {
          size_t wt = ((size_t)(c * 4 + g) * 32 + (s * 2 + ks)) * 512 + lane * 8;
          f16x8 bh = ldh8(&W2h[wt]), bl = ldh8(&W2l[wt]);
#pragma unroll
          for (int f = 0; f < 2; ++f) {
            acc[f][g] = MFMA16(hh2[f], bh, acc[f][g]);
            acc[f][g] = MFMA16(hh2[f], bl, acc[f][g]);
          }
        }
      }
    }
    __builtin_amdgcn_s_setprio(0);
    if (p < 7) {
      f32x4 a1[2][2] = {};
      gemm1p(p + 1, a1); hswrp(p + 1, a1);
    }
  }
  __syncthreads();

  float* mytr = trw + w * 1088;
  const int lr = lane >> 2, cb = (lane & 3) * 16;
  const int colL = c * 64 + cb;
#pragma unroll
  for (int f = 0; f < 2; ++f) {
#pragma unroll
    for (int g = 0; g < 4; ++g)
#pragma unroll
      for (int r = 0; r < 4; ++r)
        mytr[((lane >> 4) * 4 + r) * 68 + g * 16 + (lane & 15)] = acc[f][g][r];
    int tl = h * 32 + f * 16 + lr;
    int R = blk * 64 + tl;
    float mk = keep[R];
    size_t base = ((size_t)(R >> 4) * 8 + (colL >> 5)) * 512;
    int q0 = (colL & 31) >> 3;
    HF8 rh0, rh1, rl0, rl1;
    rh0.v = ldh8(&Xch[base + (q0 * 16 + lr) * 8]);
    rh1.v = ldh8(&Xch[base + ((q0 + 1) * 16 + lr) * 8]);
    rl0.v = ldh8(&Xcl[base + (q0 * 16 + lr) * 8]);
    rl1.v = ldh8(&Xcl[base + ((q0 + 1) * 16 + lr) * 8]);
    float z[16];
#pragma unroll
    for (int i = 0; i < 4; ++i) {
      float4 t = *(const float4*)&mytr[lr * 68 + cb + i * 4];
      float4 bb = *(const float4*)&b2[colL + i * 4];
      float tv[4] = {t.x + bb.x, t.y + bb.y, t.z + bb.z, t.w + bb.w};
#pragma unroll
      for (int q2 = 0; q2 < 4; ++q2) {
        int ii = i * 4 + q2;
        float rv = (ii < 8) ? h2f(rh0.u[ii]) + h2f(rl0.u[ii])
                            : h2f(rh1.u[ii - 8]) + h2f(rl1.u[ii - 8]);
        z[ii] = (rv + tv[q2]) * mk;
      }
    }
    if (FINAL) {
#pragma unroll
      for (int i = 0; i < 4; ++i)
        *(float4*)&outf[(size_t)R * 256 + colL + i * 4] = *(const float4*)&z[i * 4];
    } else {
      HF8 h0, l0, h1, l1;
#pragma unroll
      for (int i = 0; i < 16; ++i) {
        ushort hh, ll; split_h(z[i], hh, ll);
        if (i < 8) { h0.u[i] = hh; l0.u[i] = ll; } else { h1.u[i - 8] = hh; l1.u[i - 8] = ll; }
      }
      *(f16x8*)&Oh[base + (q0 * 16 + lr) * 8] = h0.v;
      *(f16x8*)&Oh[base + ((q0 + 1) * 16 + lr) * 8] = h1.v;
      *(f16x8*)&Ol[base + (q0 * 16 + lr) * 8] = l0.v;
      *(f16x8*)&Ol[base + ((q0 + 1) * 16 + lr) * 8] = l1.v;
    }
  }
}

// X fp32 [rows][256] -> A-frag fp16 hl (nkt=8)
__global__ __launch_bounds__(256) void k_xprep(const float* __restrict__ X,
    ushort* __restrict__ Dh, ushort* __restrict__ Dl) {
  int t = blockIdx.x * 4 + (threadIdx.x >> 6);
  int lane = threadIdx.x & 63;
  int rt = t >> 3, kt = t & 7;
  const float* sp = X + (size_t)(rt * 16 + (lane & 15)) * 256 + kt * 32 + (lane >> 4) * 8;
  float4 a = *(const float4*)sp;
  float4 b = *(const float4*)(sp + 4);
  float xs[8] = {a.x, a.y, a.z, a.w, b.x, b.y, b.z, b.w};
  HF8 h, l;
#pragma unroll
  for (int e = 0; e < 8; ++e) split_h(xs[e], h.u[e], l.u[e]);
  *(f16x8*)&Dh[(size_t)t * 512 + lane * 8] = h.v;
  *(f16x8*)&Dl[(size_t)t * 512 + lane * 8] = l.v;
}

// W fp32 [K][Nout] -> B-frag fp16 hl [Nout/16][K/32]
__global__ __launch_bounds__(256) void k_wprep(const float* __restrict__ W,
    ushort* __restrict__ Dh, ushort* __restrict__ Dl, int Nout, int K) {
  int t = blockIdx.x * 4 + (threadIdx.x >> 6);
  int lane = threadIdx.x & 63;
  int nkt = K >> 5;
  int nt = t / nkt, kt = t % nkt;
  int n = nt * 16 + (lane & 15);
  int k0 = kt * 32 + (lane >> 4) * 8;
  HF8 h, l;
#pragma unroll
  for (int e = 0; e < 8; ++e) {
    float x = W[(size_t)(k0 + e) * Nout + n];
    split_h(x, h.u[e], l.u[e]);
  }
  *(f16x8*)&Dh[(size_t)t * 512 + lane * 8] = h.v;
  *(f16x8*)&Dl[(size_t)t * 512 + lane * 8] = l.v;
}

extern "C" void kernel_launch(void* const* d_in, const int* in_sizes, int n_in,
                              void* d_out, int out_size, void* d_ws, size_t ws_size,
                              hipStream_t stream) {
  const float* slots  = (const float*)d_in[0];
  const float* keep   = (const float*)d_in[1];
  const float* fw_w1  = (const float*)d_in[2];
  const float* fw_b1  = (const float*)d_in[3];
  const float* fw_w2  = (const float*)d_in[4];
  const float* fw_b2  = (const float*)d_in[5];
  const float* fw_lnw = (const float*)d_in[6];
  const float* fw_lnb = (const float*)d_in[7];
  const float* bw_w1  = (const float*)d_in[8];
  const float* bw_b1  = (const float*)d_in[9];
  const float* bw_w2  = (const float*)d_in[10];
  const float* bw_b2  = (const float*)d_in[11];
  const float* bw_lnw = (const float*)d_in[12];
  const float* bw_lnb = (const float*)d_in[13];
  const float* mg_w   = (const float*)d_in[14];
  const float* mg_b   = (const float*)d_in[15];
  const float* nm_w   = (const float*)d_in[16];
  const float* nm_b   = (const float*)d_in[17];
  const float* ffn_lnw= (const float*)d_in[18];
  const float* ffn_lnb= (const float*)d_in[19];
  const float* ffn_w1 = (const float*)d_in[20];
  const float* ffn_b1 = (const float*)d_in[21];
  const float* ffn_w2 = (const float*)d_in[22];
  const float* ffn_b2 = (const float*)d_in[23];
  (void)n_in; (void)out_size;

  const int N = in_sizes[0] / 256;
  float* out = (float*)d_out;

  size_t off = 0;
  char* wsb = (char*)d_ws;
  auto allocU = [&](size_t elems) -> ushort* {
    void* p = wsb + off;
    off = (off + elems * 2 + 255) & ~(size_t)255;
    return (ushort*)p;
  };

  struct LayerW {
    ushort *fw1h, *fw1l, *bw1h, *bw1l, *fw2h, *fw2l, *bw2h, *bw2l;
    ushort *mgh, *mgl, *f1h, *f1l, *f2h, *f2l;
  } lw[2];
  for (int L = 0; L < 2; ++L) {
    lw[L].fw1h = allocU(131072); lw[L].fw1l = allocU(131072);
    lw[L].bw1h = allocU(131072); lw[L].bw1l = allocU(131072);
    lw[L].fw2h = allocU(131072); lw[L].fw2l = allocU(131072);
    lw[L].bw2h = allocU(131072); lw[L].bw2l = allocU(131072);
    lw[L].mgh  = allocU(131072); lw[L].mgl  = allocU(131072);
    lw[L].f1h  = allocU(262144); lw[L].f1l  = allocU(262144);
    lw[L].f2h  = allocU(262144); lw[L].f2l  = allocU(262144);
  }

  size_t remain = ws_size > off + 4096 ? ws_size - off - 4096 : 0;
  int chunk = N;
  while ((size_t)chunk * 4608 > remain && chunk > 512) chunk >>= 1;

  ushort* Xfh = allocU((size_t)chunk * 256); ushort* Xfl = allocU((size_t)chunk * 256);
  ushort* Fh  = allocU((size_t)chunk * 512);
  ushort* Xch = allocU((size_t)chunk * 256); ushort* Xcl = allocU((size_t)chunk * 256);
  ushort* Hbh = allocU((size_t)chunk * 256);
  ushort* X2h = allocU((size_t)chunk * 256); ushort* X2l = allocU((size_t)chunk * 256);

  for (int L = 0; L < 2; ++L) {
    k_wprep<<<64, 256, 0, stream>>>(fw_w1 + (size_t)L * 131072, lw[L].fw1h, lw[L].fw1l, 512, 256);
    k_wprep<<<64, 256, 0, stream>>>(bw_w1 + (size_t)L * 131072, lw[L].bw1h, lw[L].bw1l, 512, 256);
    k_wprep<<<64, 256, 0, stream>>>(fw_w2 + (size_t)L * 131072, lw[L].fw2h, lw[L].fw2l, 256, 512);
    k_wprep<<<64, 256, 0, stream>>>(bw_w2 + (size_t)L * 131072, lw[L].bw2h, lw[L].bw2l, 256, 512);
    k_wprep<<<64, 256, 0, stream>>>(mg_w + (size_t)L * 131072, lw[L].mgh, lw[L].mgl, 256, 512);
    k_wprep<<<128, 256, 0, stream>>>(ffn_w1 + (size_t)L * 262144, lw[L].f1h, lw[L].f1l, 1024, 256);
    k_wprep<<<128, 256, 0, stream>>>(ffn_w2 + (size_t)L * 262144, lw[L].f2h, lw[L].f2l, 256, 1024);
  }

  for (int c0 = 0; c0 < N; c0 += chunk) {
    k_xprep<<<(chunk / 16) * 2, 256, 0, stream>>>(slots + (size_t)c0 * 256, Xfh, Xfl);
    const int gx = chunk / 64;
    for (int L = 0; L < 2; ++L) {
      const ushort* Xh = (L == 0) ? Xfh : X2h;
      const ushort* Xl = (L == 0) ? Xfl : X2l;
      k_lin12<<<dim3(gx, 2), 512, 0, stream>>>(
          Xh,
          lw[L].fw1h, lw[L].fw1l, lw[L].bw1h, lw[L].bw1l,
          lw[L].fw2h, lw[L].fw2l, lw[L].bw2h, lw[L].bw2l,
          fw_b1 + (size_t)L * 512, bw_b1 + (size_t)L * 512,
          fw_b2 + (size_t)L * 256, bw_b2 + (size_t)L * 256,
          fw_lnw + (size_t)L * 256, fw_lnb + (size_t)L * 256,
          bw_lnw + (size_t)L * 256, bw_lnb + (size_t)L * 256,
          Fh);
      k_mergep<<<gx, 512, 0, stream>>>(
          Fh, lw[L].mgh, lw[L].mgl, mg_b + (size_t)L * 256,
          Xh, Xl,
          nm_w + (size_t)L * 256, nm_b + (size_t)L * 256,
          ffn_lnw + (size_t)L * 256, ffn_lnb + (size_t)L * 256,
          Xch, Xcl, Hbh);
      if (L == 0) {
        k_ffn<false><<<gx, 512, 0, stream>>>(
            Hbh, lw[L].f1h, lw[L].f1l, ffn_b1 + (size_t)L * 1024,
            lw[L].f2h, lw[L].f2l, ffn_b2 + (size_t)L * 256,
            Xch, Xcl, keep + c0, nullptr, X2h, X2l);
      } else {
        k_ffn<true><<<gx, 512, 0, stream>>>(
            Hbh, lw[L].f1h, lw[L].f1l, ffn_b1 + (size_t)L * 1024,
            lw[L].f2h, lw[L].f2l, ffn_b2 + (size_t)L * 256,
            Xch, Xcl, keep + c0, out + (size_t)c0 * 256, nullptr, nullptr);
      }
    }
  }
}

// Round 20
// 2208.568 us; speedup vs baseline: 1.4871x; 1.0001x over previous
//
#include <hip/hip_runtime.h>
#include <math.h>
#include <stdint.h>

typedef _Float16 f16x8 __attribute__((ext_vector_type(8)));
typedef __attribute__((ext_vector_type(4))) float f32x4;

#define MFMA16(a, b, c) __builtin_amdgcn_mfma_f32_16x16x32_f16(a, b, c, 0, 0, 0)

union H16 { _Float16 f; ushort u; };
union HF8 { ushort u[8]; f16x8 v; };

__device__ __forceinline__ ushort f2h(float x) { H16 t; t.f = (_Float16)x; return t.u; }
__device__ __forceinline__ float h2f(ushort u) { H16 t; t.u = u; return (float)t.f; }
__device__ __forceinline__ void split_h(float x, ushort& h, ushort& l) {
  h = f2h(x);
  l = f2h(x - h2f(h));
}
__device__ __forceinline__ f16x8 ldh8(const ushort* p) { return *(const f16x8*)p; }

__device__ __forceinline__ float silu_f(float x) {
  float e = __builtin_amdgcn_exp2f(x * -1.44269504089f);
  return x * __builtin_amdgcn_rcpf(1.f + e);
}
__device__ __forceinline__ float gelu_f(float x) {
  float z = fabsf(x) * 0.70710678118654752f;
  float t = __builtin_amdgcn_rcpf(fmaf(0.3275911f, z, 1.f));
  float poly = t * (0.254829592f + t * (-0.284496736f + t * (1.421413741f +
               t * (-1.453152027f + t * 1.061405429f))));
  float e = __builtin_amdgcn_exp2f(-z * z * 1.44269504089f);
  float erfz = copysignf(1.f - poly * e, x);
  return 0.5f * x * (1.f + erfz);
}

// write-drain barrier: LDS writes visible, global loads stay in flight
__device__ __forceinline__ void lgkm_barrier() {
  asm volatile("s_waitcnt lgkmcnt(0)" ::: "memory");
  __builtin_amdgcn_s_barrier();
}

// Fragment-linear: buffer[rt][kt][lane][8] ushorts (tile=512).
// A-frag: lane holds row lane&15, k=kt*32+(lane>>4)*8+e.
// C-frag [m89]: col=lane&15(+g*16), row=(lane>>4)*4+r(+f*16).
// LDS hand-off: single fp16 plane, 512 ushorts/tile, XOR swizzle:
//   idx = ((q*16+t)*8+e) ^ (((t>>2)&3)*8); read b128 at (lane*8)^swz.

__device__ __forceinline__ f16x8 rdtile16(const ushort* src, int T, int lane) {
  int idx = T * 512 + ((lane * 8) ^ (((lane >> 2) & 3) * 8));
  return *(const f16x8*)&src[idx];
}

// ---------------------------------------------------------------------------
// KA: F_br = LN_br(silu(X @ W1b + b1) @ W2b + b2).  64 tok/block, branch =
// blockIdx.y. 4 phases x 2 slabs (r15-proven structure) + T5 setprio around
// GEMM2 MFMA cluster.
// ---------------------------------------------------------------------------
__global__ __launch_bounds__(512) void k_lin12(
    const ushort* __restrict__ Xh,
    const ushort* __restrict__ fW1h, const ushort* __restrict__ fW1l,
    const ushort* __restrict__ bW1h, const ushort* __restrict__ bW1l,
    const ushort* __restrict__ fW2h, const ushort* __restrict__ fW2l,
    const ushort* __restrict__ bW2h, const ushort* __restrict__ bW2l,
    const float* __restrict__ fb1, const float* __restrict__ bb1,
    const float* __restrict__ fb2, const float* __restrict__ bb2,
    const float* __restrict__ flw, const float* __restrict__ flb,
    const float* __restrict__ blw, const float* __restrict__ blb,
    ushort* __restrict__ Fh) {
  __shared__ __align__(16) char lraw[36864];
  __shared__ float st[512];
  ushort* Hs16 = (ushort*)lraw;  // [2 dbuf][2 slab][4096] ushorts = 32KB
  float* trw = (float*)lraw;     // [8][1088] (epilogue alias)

  const int tid = threadIdx.x, lane = tid & 63, w = tid >> 6;
  const int h = w >> 2, c = w & 3;
  const int blk = blockIdx.x, br = blockIdx.y;
  const ushort* W1h = br ? bW1h : fW1h; const ushort* W1l = br ? bW1l : fW1l;
  const ushort* W2h = br ? bW2h : fW2h; const ushort* W2l = br ? bW2l : fW2l;
  const float* b1 = br ? bb1 : fb1;
  const float* b2 = br ? bb2 : fb2;
  const float* lw = br ? blw : flw;
  const float* lb = br ? blb : flb;

  f32x4 acc[2][4];
#pragma unroll
  for (int f = 0; f < 2; ++f)
#pragma unroll
    for (int g = 0; g < 4; ++g) acc[f][g] = (f32x4){0.f, 0.f, 0.f, 0.f};

  // gemm1 for a phase: both slabs (2p, 2p+1); A loaded once per kt.
  auto gemm1p = [&](int p, f32x4 a1[2][2]) {
#pragma unroll 4
    for (int kt = 0; kt < 8; ++kt) {
      f16x8 ah[2];
#pragma unroll
      for (int f = 0; f < 2; ++f) {
        size_t at = ((size_t)(blk * 4 + h * 2 + f) * 8 + kt) * 512 + lane * 8;
        ah[f] = ldh8(&Xh[at]);
      }
#pragma unroll
      for (int sl = 0; sl < 2; ++sl) {
        int s = p * 2 + sl;
        size_t wt = ((size_t)(s * 4 + c) * 8 + kt) * 512 + lane * 8;
        f16x8 bh = ldh8(&W1h[wt]), bl = ldh8(&W1l[wt]);
#pragma unroll
        for (int f = 0; f < 2; ++f) {
          a1[sl][f] = MFMA16(ah[f], bh, a1[sl][f]);
          a1[sl][f] = MFMA16(ah[f], bl, a1[sl][f]);
        }
      }
    }
  };
  auto hswrp = [&](int p, f32x4 a1[2][2]) {
    const int ktile = c >> 1;
    const int q = (c & 1) * 2 + ((lane & 15) >> 3);
    const int e = lane & 7;
#pragma unroll
    for (int sl = 0; sl < 2; ++sl) {
      int s = p * 2 + sl;
      ushort* dst = Hs16 + (p & 1) * 8192 + sl * 4096;
      const float bias1 = b1[s * 64 + c * 16 + (lane & 15)];
#pragma unroll
      for (int f = 0; f < 2; ++f) {
        const int rt = h * 2 + f;
#pragma unroll
        for (int r = 0; r < 4; ++r) {
          float x = silu_f(a1[sl][f][r] + bias1);
          int t16 = (lane >> 4) * 4 + r;
          int idx = ((q * 16 + t16) * 8 + e) ^ (((t16 >> 2) & 3) * 8);
          dst[(rt * 2 + ktile) * 512 + idx] = f2h(x);
        }
      }
    }
  };

  {
    f32x4 a1[2][2] = {};
    gemm1p(0, a1); hswrp(0, a1);
  }
#pragma unroll 1
  for (int p = 0; p < 4; ++p) {
    lgkm_barrier();
    const ushort* src = Hs16 + (p & 1) * 8192;
    __builtin_amdgcn_s_setprio(1);
#pragma unroll
    for (int sl = 0; sl < 2; ++sl) {
      int s = p * 2 + sl;
#pragma unroll
      for (int ks = 0; ks < 2; ++ks) {
        f16x8 hh2[2];
#pragma unroll
        for (int f = 0; f < 2; ++f)
          hh2[f] = rdtile16(src, sl * 8 + (h * 2 + f) * 2 + ks, lane);
#pragma unroll
        for (int g = 0; g < 4; ++g) {
          size_t wt = ((size_t)(c * 4 + g) * 16 + (s * 2 + ks)) * 512 + lane * 8;
          f16x8 bh = ldh8(&W2h[wt]), bl = ldh8(&W2l[wt]);
#pragma unroll
          for (int f = 0; f < 2; ++f) {
            acc[f][g] = MFMA16(hh2[f], bh, acc[f][g]);
            acc[f][g] = MFMA16(hh2[f], bl, acc[f][g]);
          }
        }
      }
    }
    __builtin_amdgcn_s_setprio(0);
    if (p < 3) {
      f32x4 a1[2][2] = {};
      gemm1p(p + 1, a1); hswrp(p + 1, a1);
    }
  }
  __syncthreads();  // all Hs reads done; trw aliases the region

  // epilogue: bias2 + branch LN; coalesced via per-wave padded transpose
  float* mytr = trw + w * 1088;
  const int lr = lane >> 2, cb = (lane & 3) * 16;
  const int colL = c * 64 + cb;
  float y[2][16];
#pragma unroll
  for (int f = 0; f < 2; ++f) {
#pragma unroll
    for (int g = 0; g < 4; ++g)
#pragma unroll
      for (int r = 0; r < 4; ++r)
        mytr[((lane >> 4) * 4 + r) * 68 + g * 16 + (lane & 15)] = acc[f][g][r];
    float s1 = 0.f, s2 = 0.f;
#pragma unroll
    for (int i = 0; i < 4; ++i) {
      float4 t = *(const float4*)&mytr[lr * 68 + cb + i * 4];
      float4 bb = *(const float4*)&b2[colL + i * 4];
      y[f][i * 4 + 0] = t.x + bb.x; y[f][i * 4 + 1] = t.y + bb.y;
      y[f][i * 4 + 2] = t.z + bb.z; y[f][i * 4 + 3] = t.w + bb.w;
#pragma unroll
      for (int q2 = 0; q2 < 4; ++q2) { float v = y[f][i * 4 + q2]; s1 += v; s2 += v * v; }
    }
    s1 += __shfl_xor(s1, 1, 64); s2 += __shfl_xor(s2, 1, 64);
    s1 += __shfl_xor(s1, 2, 64); s2 += __shfl_xor(s2, 2, 64);
    if ((lane & 3) == 0) {
      int tl = h * 32 + f * 16 + lr;
      st[tl * 8 + c * 2] = s1; st[tl * 8 + c * 2 + 1] = s2;
    }
  }
  lgkm_barrier();
#pragma unroll
  for (int f = 0; f < 2; ++f) {
    int tl = h * 32 + f * 16 + lr;
    float s1 = st[tl * 8] + st[tl * 8 + 2] + st[tl * 8 + 4] + st[tl * 8 + 6];
    float s2 = st[tl * 8 + 1] + st[tl * 8 + 3] + st[tl * 8 + 5] + st[tl * 8 + 7];
    float mu = s1 * (1.f / 256.f);
    float rs = rsqrtf(s2 * (1.f / 256.f) - mu * mu + 1e-5f);
    HF8 h0, h1;
#pragma unroll
    for (int i = 0; i < 16; ++i) {
      float z = (y[f][i] - mu) * rs * lw[colL + i] + lb[colL + i];
      if (i < 8) h0.u[i] = f2h(z); else h1.u[i - 8] = f2h(z);
    }
    int R = blk * 64 + tl;
    int Cg = br * 256 + colL;
    size_t base = ((size_t)(R >> 4) * 16 + (Cg >> 5)) * 512;
    int q0 = (Cg & 31) >> 3;
    *(f16x8*)&Fh[base + (q0 * 16 + lr) * 8] = h0.v;
    *(f16x8*)&Fh[base + ((q0 + 1) * 16 + lr) * 8] = h1.v;
  }
}

// ---------------------------------------------------------------------------
// KB: M = F @ mg + b; Xc = LN(resid + M, nm); Hb = LN(Xc, ffn).
// ---------------------------------------------------------------------------
__global__ __launch_bounds__(512) void k_mergep(
    const ushort* __restrict__ Fh,
    const ushort* __restrict__ Mh, const ushort* __restrict__ Ml,
    const float* __restrict__ mgb,
    const ushort* __restrict__ Rh, const ushort* __restrict__ Rl,
    const float* __restrict__ nmw, const float* __restrict__ nmb,
    const float* __restrict__ fw, const float* __restrict__ fb,
    ushort* __restrict__ Xch, ushort* __restrict__ Xcl,
    ushort* __restrict__ Hbh) {
  __shared__ float trw[8][1088];
  __shared__ float st[512], stB[512];
  const int tid = threadIdx.x, lane = tid & 63, w = tid >> 6;
  const int h = w >> 2, c = w & 3;
  const int blk = blockIdx.x;

  f32x4 acc[2][4];
#pragma unroll
  for (int f = 0; f < 2; ++f)
#pragma unroll
    for (int g = 0; g < 4; ++g) acc[f][g] = (f32x4){0.f, 0.f, 0.f, 0.f};

#pragma unroll 2
  for (int kt = 0; kt < 16; ++kt) {
    f16x8 ah[2];
#pragma unroll
    for (int f = 0; f < 2; ++f) {
      size_t at = ((size_t)(blk * 4 + h * 2 + f) * 16 + kt) * 512 + lane * 8;
      ah[f] = ldh8(&Fh[at]);
    }
#pragma unroll
    for (int g = 0; g < 4; ++g) {
      size_t wt = ((size_t)(c * 4 + g) * 16 + kt) * 512 + lane * 8;
      f16x8 bh = ldh8(&Mh[wt]), bl = ldh8(&Ml[wt]);
#pragma unroll
      for (int f = 0; f < 2; ++f) {
        acc[f][g] = MFMA16(ah[f], bh, acc[f][g]);
        acc[f][g] = MFMA16(ah[f], bl, acc[f][g]);
      }
    }
  }

  float* mytr = &trw[w][0];
  const int lr = lane >> 2, cb = (lane & 3) * 16;
  const int colL = c * 64 + cb;
  float y[2][16];
#pragma unroll
  for (int f = 0; f < 2; ++f) {
#pragma unroll
    for (int g = 0; g < 4; ++g)
#pragma unroll
      for (int r = 0; r < 4; ++r)
        mytr[((lane >> 4) * 4 + r) * 68 + g * 16 + (lane & 15)] = acc[f][g][r];
    int tl = h * 32 + f * 16 + lr;
    int R = blk * 64 + tl;
    size_t base = ((size_t)(R >> 4) * 8 + (colL >> 5)) * 512;
    int q0 = (colL & 31) >> 3;
    HF8 rh0, rh1, rl0, rl1;
    rh0.v = ldh8(&Rh[base + (q0 * 16 + lr) * 8]);
    rh1.v = ldh8(&Rh[base + ((q0 + 1) * 16 + lr) * 8]);
    rl0.v = ldh8(&Rl[base + (q0 * 16 + lr) * 8]);
    rl1.v = ldh8(&Rl[base + ((q0 + 1) * 16 + lr) * 8]);
    float s1 = 0.f, s2 = 0.f;
#pragma unroll
    for (int i = 0; i < 4; ++i) {
      float4 t = *(const float4*)&mytr[lr * 68 + cb + i * 4];
      float4 bb = *(const float4*)&mgb[colL + i * 4];
      float tv[4] = {t.x + bb.x, t.y + bb.y, t.z + bb.z, t.w + bb.w};
#pragma unroll
      for (int q2 = 0; q2 < 4; ++q2) {
        int ii = i * 4 + q2;
        float rv = (ii < 8) ? h2f(rh0.u[ii]) + h2f(rl0.u[ii])
                            : h2f(rh1.u[ii - 8]) + h2f(rl1.u[ii - 8]);
        float v = tv[q2] + rv;
        y[f][ii] = v; s1 += v; s2 += v * v;
      }
    }
    s1 += __shfl_xor(s1, 1, 64); s2 += __shfl_xor(s2, 1, 64);
    s1 += __shfl_xor(s1, 2, 64); s2 += __shfl_xor(s2, 2, 64);
    if ((lane & 3) == 0) { st[tl * 8 + c * 2] = s1; st[tl * 8 + c * 2 + 1] = s2; }
  }
  __syncthreads();
#pragma unroll
  for (int f = 0; f < 2; ++f) {
    int tl = h * 32 + f * 16 + lr;
    int R = blk * 64 + tl;
    float s1 = st[tl * 8] + st[tl * 8 + 2] + st[tl * 8 + 4] + st[tl * 8 + 6];
    float s2 = st[tl * 8 + 1] + st[tl * 8 + 3] + st[tl * 8 + 5] + st[tl * 8 + 7];
    float mu = s1 * (1.f / 256.f);
    float rs = rsqrtf(s2 * (1.f / 256.f) - mu * mu + 1e-5f);
    HF8 h0, l0, h1, l1;
    float t1 = 0.f, t2 = 0.f;
#pragma unroll
    for (int i = 0; i < 16; ++i) {
      float x = (y[f][i] - mu) * rs * nmw[colL + i] + nmb[colL + i];
      y[f][i] = x; t1 += x; t2 += x * x;
      ushort hh, ll; split_h(x, hh, ll);
      if (i < 8) { h0.u[i] = hh; l0.u[i] = ll; } else { h1.u[i - 8] = hh; l1.u[i - 8] = ll; }
    }
    size_t base = ((size_t)(R >> 4) * 8 + (colL >> 5)) * 512;
    int q0 = (colL & 31) >> 3;
    *(f16x8*)&Xch[base + (q0 * 16 + lr) * 8] = h0.v;
    *(f16x8*)&Xch[base + ((q0 + 1) * 16 + lr) * 8] = h1.v;
    *(f16x8*)&Xcl[base + (q0 * 16 + lr) * 8] = l0.v;
    *(f16x8*)&Xcl[base + ((q0 + 1) * 16 + lr) * 8] = l1.v;
    t1 += __shfl_xor(t1, 1, 64); t2 += __shfl_xor(t2, 1, 64);
    t1 += __shfl_xor(t1, 2, 64); t2 += __shfl_xor(t2, 2, 64);
    if ((lane & 3) == 0) { stB[tl * 8 + c * 2] = t1; stB[tl * 8 + c * 2 + 1] = t2; }
  }
  __syncthreads();
#pragma unroll
  for (int f = 0; f < 2; ++f) {
    int tl = h * 32 + f * 16 + lr;
    int R = blk * 64 + tl;
    float s1 = stB[tl * 8] + stB[tl * 8 + 2] + stB[tl * 8 + 4] + stB[tl * 8 + 6];
    float s2 = stB[tl * 8 + 1] + stB[tl * 8 + 3] + stB[tl * 8 + 5] + stB[tl * 8 + 7];
    float mu = s1 * (1.f / 256.f);
    float rs = rsqrtf(s2 * (1.f / 256.f) - mu * mu + 1e-5f);
    HF8 h0, h1;
#pragma unroll
    for (int i = 0; i < 16; ++i) {
      float z = (y[f][i] - mu) * rs * fw[colL + i] + fb[colL + i];
      if (i < 8) h0.u[i] = f2h(z); else h1.u[i - 8] = f2h(z);
    }
    size_t base = ((size_t)(R >> 4) * 8 + (colL >> 5)) * 512;
    int q0 = (colL & 31) >> 3;
    *(f16x8*)&Hbh[base + (q0 * 16 + lr) * 8] = h0.v;
    *(f16x8*)&Hbh[base + ((q0 + 1) * 16 + lr) * 8] = h1.v;
  }
}

// ---------------------------------------------------------------------------
// KC: out = (Xc + gelu(Hb @ W1 + b1) @ W2 + b2) * mask. 64 tok/block,
// 8 phases x 2 slabs (r15-proven) + T5 setprio around GEMM2 MFMA.
// ---------------------------------------------------------------------------
template<bool FINAL>
__global__ __launch_bounds__(512) void k_ffn(
    const ushort* __restrict__ Hbh,
    const ushort* __restrict__ W1h, const ushort* __restrict__ W1l,
    const float* __restrict__ b1,
    const ushort* __restrict__ W2h, const ushort* __restrict__ W2l,
    const float* __restrict__ b2,
    const ushort* __restrict__ Xch, const ushort* __restrict__ Xcl,
    const float* __restrict__ keep,
    float* __restrict__ outf, ushort* __restrict__ Oh, ushort* __restrict__ Ol) {
  __shared__ __align__(16) char lraw[36864];
  ushort* Hs16 = (ushort*)lraw;  // [2 dbuf][2 slab][4096] = 32KB
  float* trw = (float*)lraw;     // epilogue alias

  const int tid = threadIdx.x, lane = tid & 63, w = tid >> 6;
  const int h = w >> 2, c = w & 3;
  const int blk = blockIdx.x;

  f32x4 acc[2][4];
#pragma unroll
  for (int f = 0; f < 2; ++f)
#pragma unroll
    for (int g = 0; g < 4; ++g) acc[f][g] = (f32x4){0.f, 0.f, 0.f, 0.f};

  auto gemm1p = [&](int p, f32x4 a1[2][2]) {
#pragma unroll 4
    for (int kt = 0; kt < 8; ++kt) {
      f16x8 ah[2];
#pragma unroll
      for (int f = 0; f < 2; ++f) {
        size_t at = ((size_t)(blk * 4 + h * 2 + f) * 8 + kt) * 512 + lane * 8;
        ah[f] = ldh8(&Hbh[at]);
      }
#pragma unroll
      for (int sl = 0; sl < 2; ++sl) {
        int s = p * 2 + sl;
        size_t wt = ((size_t)(s * 4 + c) * 8 + kt) * 512 + lane * 8;
        f16x8 bh = ldh8(&W1h[wt]), bl = ldh8(&W1l[wt]);
#pragma unroll
        for (int f = 0; f < 2; ++f) {
          a1[sl][f] = MFMA16(ah[f], bh, a1[sl][f]);
          a1[sl][f] = MFMA16(ah[f], bl, a1[sl][f]);
        }
      }
    }
  };
  auto hswrp = [&](int p, f32x4 a1[2][2]) {
    const int ktile = c >> 1;
    const int q = (c & 1) * 2 + ((lane & 15) >> 3);
    const int e = lane & 7;
#pragma unroll
    for (int sl = 0; sl < 2; ++sl) {
      int s = p * 2 + sl;
      ushort* dst = Hs16 + (p & 1) * 8192 + sl * 4096;
      const float bias1 = b1[s * 64 + c * 16 + (lane & 15)];
#pragma unroll
      for (int f = 0; f < 2; ++f) {
        const int rt = h * 2 + f;
#pragma unroll
        for (int r = 0; r < 4; ++r) {
          float x = gelu_f(a1[sl][f][r] + bias1);
          int t16 = (lane >> 4) * 4 + r;
          int idx = ((q * 16 + t16) * 8 + e) ^ (((t16 >> 2) & 3) * 8);
          dst[(rt * 2 + ktile) * 512 + idx] = f2h(x);
        }
      }
    }
  };

  {
    f32x4 a1[2][2] = {};
    gemm1p(0, a1); hswrp(0, a1);
  }
#pragma unroll 1
  for (int p = 0; p < 8; ++p) {
    lgkm_barrier();
    const ushort* src = Hs16 + (p & 1) * 8192;
    __builtin_amdgcn_s_setprio(1);
#pragma unroll
    for (int sl = 0; sl < 2; ++sl) {
      int s = p * 2 + sl;
#pragma unroll
      for (int ks = 0; ks < 2; ++ks) {
        f16x8 hh2[2];
#pragma unroll
        for (int f = 0; f < 2; ++f)
          hh2[f] = rdtile16(src, sl * 8 + (h * 2 + f) * 2 + ks, lane);
#pragma unroll
        for (int g = 0; g < 4; ++g) {
          size_t wt = ((size_t)(c * 4 + g) * 32 + (s * 2 + ks)) * 512 + lane * 8;
          f16x8 bh = ldh8(&W2h[wt]), bl = ldh8(&W2l[wt]);
#pragma unroll
          for (int f = 0; f < 2; ++f) {
            acc[f][g] = MFMA16(hh2[f], bh, acc[f][g]);
            acc[f][g] = MFMA16(hh2[f], bl, acc[f][g]);
          }
        }
      }
    }
    __builtin_amdgcn_s_setprio(0);
    if (p < 7) {
      f32x4 a1[2][2] = {};
      gemm1p(p + 1, a1); hswrp(p + 1, a1);
    }
  }
  __syncthreads();

  float* mytr = trw + w * 1088;
  const int lr = lane >> 2, cb = (lane & 3) * 16;
  const int colL = c * 64 + cb;
#pragma unroll
  for (int f = 0; f < 2; ++f) {
#pragma unroll
    for (int g = 0; g < 4; ++g)
#pragma unroll
      for (int r = 0; r < 4; ++r)
        mytr[((lane >> 4) * 4 + r) * 68 + g * 16 + (lane & 15)] = acc[f][g][r];
    int tl = h * 32 + f * 16 + lr;
    int R = blk * 64 + tl;
    float mk = keep[R];
    size_t base = ((size_t)(R >> 4) * 8 + (colL >> 5)) * 512;
    int q0 = (colL & 31) >> 3;
    HF8 rh0, rh1, rl0, rl1;
    rh0.v = ldh8(&Xch[base + (q0 * 16 + lr) * 8]);
    rh1.v = ldh8(&Xch[base + ((q0 + 1) * 16 + lr) * 8]);
    rl0.v = ldh8(&Xcl[base + (q0 * 16 + lr) * 8]);
    rl1.v = ldh8(&Xcl[base + ((q0 + 1) * 16 + lr) * 8]);
    float z[16];
#pragma unroll
    for (int i = 0; i < 4; ++i) {
      float4 t = *(const float4*)&mytr[lr * 68 + cb + i * 4];
      float4 bb = *(const float4*)&b2[colL + i * 4];
      float tv[4] = {t.x + bb.x, t.y + bb.y, t.z + bb.z, t.w + bb.w};
#pragma unroll
      for (int q2 = 0; q2 < 4; ++q2) {
        int ii = i * 4 + q2;
        float rv = (ii < 8) ? h2f(rh0.u[ii]) + h2f(rl0.u[ii])
                            : h2f(rh1.u[ii - 8]) + h2f(rl1.u[ii - 8]);
        z[ii] = (rv + tv[q2]) * mk;
      }
    }
    if (FINAL) {
#pragma unroll
      for (int i = 0; i < 4; ++i)
        *(float4*)&outf[(size_t)R * 256 + colL + i * 4] = *(const float4*)&z[i * 4];
    } else {
      HF8 h0, l0, h1, l1;
#pragma unroll
      for (int i = 0; i < 16; ++i) {
        ushort hh, ll; split_h(z[i], hh, ll);
        if (i < 8) { h0.u[i] = hh; l0.u[i] = ll; } else { h1.u[i - 8] = hh; l1.u[i - 8] = ll; }
      }
      *(f16x8*)&Oh[base + (q0 * 16 + lr) * 8] = h0.v;
      *(f16x8*)&Oh[base + ((q0 + 1) * 16 + lr) * 8] = h1.v;
      *(f16x8*)&Ol[base + (q0 * 16 + lr) * 8] = l0.v;
      *(f16x8*)&Ol[base + ((q0 + 1) * 16 + lr) * 8] = l1.v;
    }
  }
}

// X fp32 [rows][256] -> A-frag fp16 hl (nkt=8)
__global__ __launch_bounds__(256) void k_xprep(const float* __restrict__ X,
    ushort* __restrict__ Dh, ushort* __restrict__ Dl) {
  int t = blockIdx.x * 4 + (threadIdx.x >> 6);
  int lane = threadIdx.x & 63;
  int rt = t >> 3, kt = t & 7;
  const float* sp = X + (size_t)(rt * 16 + (lane & 15)) * 256 + kt * 32 + (lane >> 4) * 8;
  float4 a = *(const float4*)sp;
  float4 b = *(const float4*)(sp + 4);
  float xs[8] = {a.x, a.y, a.z, a.w, b.x, b.y, b.z, b.w};
  HF8 h, l;
#pragma unroll
  for (int e = 0; e < 8; ++e) split_h(xs[e], h.u[e], l.u[e]);
  *(f16x8*)&Dh[(size_t)t * 512 + lane * 8] = h.v;
  *(f16x8*)&Dl[(size_t)t * 512 + lane * 8] = l.v;
}

// W fp32 [K][Nout] -> B-frag fp16 hl [Nout/16][K/32]
__global__ __launch_bounds__(256) void k_wprep(const float* __restrict__ W,
    ushort* __restrict__ Dh, ushort* __restrict__ Dl, int Nout, int K) {
  int t = blockIdx.x * 4 + (threadIdx.x >> 6);
  int lane = threadIdx.x & 63;
  int nkt = K >> 5;
  int nt = t / nkt, kt = t % nkt;
  int n = nt * 16 + (lane & 15);
  int k0 = kt * 32 + (lane >> 4) * 8;
  HF8 h, l;
#pragma unroll
  for (int e = 0; e < 8; ++e) {
    float x = W[(size_t)(k0 + e) * Nout + n];
    split_h(x, h.u[e], l.u[e]);
  }
  *(f16x8*)&Dh[(size_t)t * 512 + lane * 8] = h.v;
  *(f16x8*)&Dl[(size_t)t * 512 + lane * 8] = l.v;
}

extern "C" void kernel_launch(void* const* d_in, const int* in_sizes, int n_in,
                              void* d_out, int out_size, void* d_ws, size_t ws_size,
                              hipStream_t stream) {
  const float* slots  = (const float*)d_in[0];
  const float* keep   = (const float*)d_in[1];
  const float* fw_w1  = (const float*)d_in[2];
  const float* fw_b1  = (const float*)d_in[3];
  const float* fw_w2  = (const float*)d_in[4];
  const float* fw_b2  = (const float*)d_in[5];
  const float* fw_lnw = (const float*)d_in[6];
  const float* fw_lnb = (const float*)d_in[7];
  const float* bw_w1  = (const float*)d_in[8];
  const float* bw_b1  = (const float*)d_in[9];
  const float* bw_w2  = (const float*)d_in[10];
  const float* bw_b2  = (const float*)d_in[11];
  const float* bw_lnw = (const float*)d_in[12];
  const float* bw_lnb = (const float*)d_in[13];
  const float* mg_w   = (const float*)d_in[14];
  const float* mg_b   = (const float*)d_in[15];
  const float* nm_w   = (const float*)d_in[16];
  const float* nm_b   = (const float*)d_in[17];
  const float* ffn_lnw= (const float*)d_in[18];
  const float* ffn_lnb= (const float*)d_in[19];
  const float* ffn_w1 = (const float*)d_in[20];
  const float* ffn_b1 = (const float*)d_in[21];
  const float* ffn_w2 = (const float*)d_in[22];
  const float* ffn_b2 = (const float*)d_in[23];
  (void)n_in; (void)out_size;

  const int N = in_sizes[0] / 256;
  float* out = (float*)d_out;

  size_t off = 0;
  char* wsb = (char*)d_ws;
  auto allocU = [&](size_t elems) -> ushort* {
    void* p = wsb + off;
    off = (off + elems * 2 + 255) & ~(size_t)255;
    return (ushort*)p;
  };

  struct LayerW {
    ushort *fw1h, *fw1l, *bw1h, *bw1l, *fw2h, *fw2l, *bw2h, *bw2l;
    ushort *mgh, *mgl, *f1h, *f1l, *f2h, *f2l;
  } lw[2];
  for (int L = 0; L < 2; ++L) {
    lw[L].fw1h = allocU(131072); lw[L].fw1l = allocU(131072);
    lw[L].bw1h = allocU(131072); lw[L].bw1l = allocU(131072);
    lw[L].fw2h = allocU(131072); lw[L].fw2l = allocU(131072);
    lw[L].bw2h = allocU(131072); lw[L].bw2l = allocU(131072);
    lw[L].mgh  = allocU(131072); lw[L].mgl  = allocU(131072);
    lw[L].f1h  = allocU(262144); lw[L].f1l  = allocU(262144);
    lw[L].f2h  = allocU(262144); lw[L].f2l  = allocU(262144);
  }

  size_t remain = ws_size > off + 4096 ? ws_size - off - 4096 : 0;
  int chunk = N;
  while ((size_t)chunk * 4608 > remain && chunk > 512) chunk >>= 1;

  ushort* Xfh = allocU((size_t)chunk * 256); ushort* Xfl = allocU((size_t)chunk * 256);
  ushort* Fh  = allocU((size_t)chunk * 512);
  ushort* Xch = allocU((size_t)chunk * 256); ushort* Xcl = allocU((size_t)chunk * 256);
  ushort* Hbh = allocU((size_t)chunk * 256);
  ushort* X2h = allocU((size_t)chunk * 256); ushort* X2l = allocU((size_t)chunk * 256);

  for (int L = 0; L < 2; ++L) {
    k_wprep<<<64, 256, 0, stream>>>(fw_w1 + (size_t)L * 131072, lw[L].fw1h, lw[L].fw1l, 512, 256);
    k_wprep<<<64, 256, 0, stream>>>(bw_w1 + (size_t)L * 131072, lw[L].bw1h, lw[L].bw1l, 512, 256);
    k_wprep<<<64, 256, 0, stream>>>(fw_w2 + (size_t)L * 131072, lw[L].fw2h, lw[L].fw2l, 256, 512);
    k_wprep<<<64, 256, 0, stream>>>(bw_w2 + (size_t)L * 131072, lw[L].bw2h, lw[L].bw2l, 256, 512);
    k_wprep<<<64, 256, 0, stream>>>(mg_w + (size_t)L * 131072, lw[L].mgh, lw[L].mgl, 256, 512);
    k_wprep<<<128, 256, 0, stream>>>(ffn_w1 + (size_t)L * 262144, lw[L].f1h, lw[L].f1l, 1024, 256);
    k_wprep<<<128, 256, 0, stream>>>(ffn_w2 + (size_t)L * 262144, lw[L].f2h, lw[L].f2l, 256, 1024);
  }

  for (int c0 = 0; c0 < N; c0 += chunk) {
    k_xprep<<<(chunk / 16) * 2, 256, 0, stream>>>(slots + (size_t)c0 * 256, Xfh, Xfl);
    const int gx = chunk / 64;
    for (int L = 0; L < 2; ++L) {
      const ushort* Xh = (L == 0) ? Xfh : X2h;
      const ushort* Xl = (L == 0) ? Xfl : X2l;
      k_lin12<<<dim3(gx, 2), 512, 0, stream>>>(
          Xh,
          lw[L].fw1h, lw[L].fw1l, lw[L].bw1h, lw[L].bw1l,
          lw[L].fw2h, lw[L].fw2l, lw[L].bw2h, lw[L].bw2l,
          fw_b1 + (size_t)L * 512, bw_b1 + (size_t)L * 512,
          fw_b2 + (size_t)L * 256, bw_b2 + (size_t)L * 256,
          fw_lnw + (size_t)L * 256, fw_lnb + (size_t)L * 256,
          bw_lnw + (size_t)L * 256, bw_lnb + (size_t)L * 256,
          Fh);
      k_mergep<<<gx, 512, 0, stream>>>(
          Fh, lw[L].mgh, lw[L].mgl, mg_b + (size_t)L * 256,
          Xh, Xl,
          nm_w + (size_t)L * 256, nm_b + (size_t)L * 256,
          ffn_lnw + (size_t)L * 256, ffn_lnb + (size_t)L * 256,
          Xch, Xcl, Hbh);
      if (L == 0) {
        k_ffn<false><<<gx, 512, 0, stream>>>(
            Hbh, lw[L].f1h, lw[L].f1l, ffn_b1 + (size_t)L * 1024,
            lw[L].f2h, lw[L].f2l, ffn_b2 + (size_t)L * 256,
            Xch, Xcl, keep + c0, nullptr, X2h, X2l);
      } else {
        k_ffn<true><<<gx, 512, 0, stream>>>(
            Hbh, lw[L].f1h, lw[L].f1l, ffn_b1 + (size_t)L * 1024,
            lw[L].f2h, lw[L].f2l, ffn_b2 + (size_t)L * 256,
            Xch, Xcl, keep + c0, out + (size_t)c0 * 256, nullptr, nullptr);
      }
    }
  }
}